// Round 8
// baseline (476.384 us; speedup 1.0000x reference)
//
#include <hip/hip_runtime.h>
#include <cstdint>

// Transformer Post-LN block, MI355X gfx950.
// B=4, L=2048, FEA=512, H=8, DK=64, FFN=2048. f32 I/O, bf16 MFMA, f32 accum.
// Round 12: attn mask VALU diet — precomputed 32-bit AND-masks per k-pair
// (maskand_k: maskPAD -> u32[b][q][k/2], 32MB). attn applies mask with ONE
// v_and per packed bf16 pair (16/it) instead of and+cmp+cndmask per score
// (~96/it). exp2 now unconditional. Fallback to r11 bitmask path when ws
// too small (template<AMASK>). Tiled K/V staging + kv-split + permlane +
// swapped QK^T kept from r11. GEMM/LN/transpose kernels unchanged.

typedef __bf16 bf16;
typedef __bf16 bf16x8 __attribute__((ext_vector_type(8)));
typedef __bf16 bf16x2 __attribute__((ext_vector_type(2)));
typedef float floatx4 __attribute__((ext_vector_type(4)));
typedef unsigned uint2v __attribute__((ext_vector_type(2)));

__device__ __forceinline__ floatx4 mfma_bf16(bf16x8 a, bf16x8 b, floatx4 c) {
  return __builtin_amdgcn_mfma_f32_16x16x32_bf16(a, b, c, 0, 0, 0);
}

// async global->LDS, 16B/lane; LDS dest = wave-uniform base + lane*16.
__device__ __forceinline__ void load_lds_16(const void* g, void* l) {
  auto gp = reinterpret_cast<const void __attribute__((address_space(1)))*>(
      reinterpret_cast<uintptr_t>(g));
  auto lp = reinterpret_cast<void __attribute__((address_space(3)))*>(
      (unsigned int)reinterpret_cast<uintptr_t>(l));
  __builtin_amdgcn_global_load_lds(gp, lp, 16, 0, 0);
}

// pack two f32 -> u32 of 2 bf16 (compiler emits v_cvt_pk_bf16_f32)
__device__ __forceinline__ unsigned pack2(float a, float b) {
  bf16x2 p;
  p[0] = (bf16)a;
  p[1] = (bf16)b;
  return __builtin_bit_cast(unsigned, p);
}

// tanh-form GELU (max |err| ~1e-3, well under 0.0988 threshold)
__device__ __forceinline__ float gelu_f(float x) {
  float t = 0.7978845608f * (x + 0.044715f * x * x * x);
  float e = __builtin_amdgcn_exp2f(t * 2.885390082f);  // e^(2t)
  float th = 1.0f - 2.0f * __builtin_amdgcn_rcpf(e + 1.0f);
  return 0.5f * x * (1.0f + th);
}

// k-plane LDS geometry: plane = rows*16B, +16B pad between planes.
#define PLANE128 2064  // 128 rows * 16B + 16B pad
#define PLANE64 1040   // 64 rows * 16B + 16B pad
#define KVCH 8320      // 8 planes * PLANE64 (one K or V tile)

// ---- f32 -> bf16 cast of qx,kx,vx (each 2^22 elems) -----------------------
__global__ void __launch_bounds__(256) cast3_k(const float* __restrict__ q,
                                               const float* __restrict__ k,
                                               const float* __restrict__ v,
                                               bf16* __restrict__ out) {
  size_t idx = ((size_t)blockIdx.x * 256 + threadIdx.x) * 8;
  int sel = (int)(idx >> 22);
  size_t off = idx & ((1u << 22) - 1);
  const float* src = (sel == 0) ? q : (sel == 1) ? k : v;
  float4 a = *(const float4*)(src + off);
  float4 b = *(const float4*)(src + off + 4);
  bf16x8 o;
  o[0] = (bf16)a.x; o[1] = (bf16)a.y; o[2] = (bf16)a.z; o[3] = (bf16)a.w;
  o[4] = (bf16)b.x; o[5] = (bf16)b.y; o[6] = (bf16)b.z; o[7] = (bf16)b.w;
  *(bf16x8*)(out + idx) = o;
}

// ---- fused weight transpose (4x 512x512) + f32->bf16 ----------------------
__global__ void __launch_bounds__(256) transpose4_k(const float* __restrict__ w0,
                                                    const float* __restrict__ w1,
                                                    const float* __restrict__ w2,
                                                    const float* __restrict__ w3,
                                                    bf16* __restrict__ o0,
                                                    bf16* __restrict__ o1,
                                                    bf16* __restrict__ o2,
                                                    bf16* __restrict__ o3) {
  const float* in = (blockIdx.z == 0) ? w0 : (blockIdx.z == 1) ? w1
                    : (blockIdx.z == 2) ? w2 : w3;
  bf16* out = (blockIdx.z == 0) ? o0 : (blockIdx.z == 1) ? o1
              : (blockIdx.z == 2) ? o2 : o3;
  __shared__ float tile[32][33];
  int m0 = blockIdx.x * 32, k0 = blockIdx.y * 32;
  int tx = threadIdx.x, ty = threadIdx.y;  // (32, 8)
  for (int i = ty; i < 32; i += 8)
    tile[i][tx] = in[(size_t)(k0 + i) * 512 + m0 + tx];
  __syncthreads();
  for (int i = ty; i < 32; i += 8)
    out[(size_t)(m0 + i) * 512 + k0 + tx] = (bf16)tile[tx][i];
}

__global__ void __launch_bounds__(256) transpose_k(const float* __restrict__ in,
                                                   bf16* __restrict__ out,
                                                   int K, int M) {
  __shared__ float tile[32][33];
  int m0 = blockIdx.x * 32, k0 = blockIdx.y * 32;
  int tx = threadIdx.x, ty = threadIdx.y;
  for (int i = ty; i < 32; i += 8)
    tile[i][tx] = in[(size_t)(k0 + i) * M + m0 + tx];
  __syncthreads();
  for (int i = ty; i < 32; i += 8)
    out[(size_t)(m0 + i) * K + k0 + tx] = (bf16)tile[tx][i];
}

// ---- maskPAD int32 -> bitmask (bit=1 keep), fallback path -----------------
__global__ void __launch_bounds__(256) maskbits_k(const int* __restrict__ m,
                                                  unsigned long long* __restrict__ out) {
  int w0 = blockIdx.x * 128 + (threadIdx.x >> 6) * 32;
  int lane = threadIdx.x & 63;
#pragma unroll 4
  for (int i = 0; i < 32; ++i) {
    int w = w0 + i;
    int v = m[(size_t)w * 64 + lane];
    unsigned long long bmask = __ballot(v != 0);
    if (lane == 0) out[w] = bmask;
  }
}

// ---- maskPAD int32 -> u32 AND-mask per k-pair -----------------------------
// out[b][q][k/2] = (m[2k]?0xFFFF:0) | (m[2k+1]?0xFFFF0000:0)
__global__ void __launch_bounds__(256) maskand_k(const int* __restrict__ m,
                                                 unsigned* __restrict__ out) {
  size_t i = ((size_t)blockIdx.x * 256 + threadIdx.x) * 8;  // 8 ints -> 4 pairs
  int4 a = *(const int4*)(m + i);
  int4 b = *(const int4*)(m + i + 4);
  uint4 o;
  o.x = (a.x ? 0xFFFFu : 0u) | (a.y ? 0xFFFF0000u : 0u);
  o.y = (a.z ? 0xFFFFu : 0u) | (a.w ? 0xFFFF0000u : 0u);
  o.z = (b.x ? 0xFFFFu : 0u) | (b.y ? 0xFFFF0000u : 0u);
  o.w = (b.z ? 0xFFFFu : 0u) | (b.w ? 0xFFFF0000u : 0u);
  *(uint4*)(out + i / 2) = o;
}

// ---- epilogue helper ------------------------------------------------------
template <int EPI>
__device__ __forceinline__ void epi_store(void* Cout, int n, int m, int M,
                                          float val) {
  if constexpr (EPI == 3) {  // GELU -> bf16
    ((bf16*)Cout)[(size_t)n * M + m] = (bf16)gelu_f(val);
  } else if constexpr (EPI == 4) {  // f32
    ((float*)Cout)[(size_t)n * M + m] = val;
  } else {  // f32 accumulate
    ((float*)Cout)[(size_t)n * M + m] += val;
  }
}

// ---- GEMM: C[N][M] = A[N][K] @ Bt[M][K]^T + bias, BK=64 -------------------
// WIDE: 128x128 tile, wave = 64x64 quadrant, acc 4x4.
// TALL: 128x64 tile, wave = 32 rows x 64 cols, acc 2x4. grid.x = M/64.
template <int EPI, bool TALL>
__global__ void __launch_bounds__(256) gemm_bt(const bf16* __restrict__ A,
                                               const bf16* __restrict__ Bt,
                                               const float* __restrict__ bias,
                                               void* __restrict__ Cout,
                                               int M, int K, int lda, int ldb) {
  __shared__ __attribute__((aligned(16))) char As[8 * PLANE128];
  __shared__ __attribute__((aligned(16))) char Bs[TALL ? 8 * PLANE64 : 8 * PLANE128];
  int tid = threadIdx.x, wave = tid >> 6, lane = tid & 63;
  int lrow = lane & 15, quad = lane >> 4;
  int n0 = blockIdx.y * 128;
  int m0 = blockIdx.x * (TALL ? 64 : 128);
  int wr = wave >> 1, wc = wave & 1;  // WIDE quadrant
  floatx4 zero4 = {0.f, 0.f, 0.f, 0.f};
  constexpr int NI = TALL ? 2 : 4;
  floatx4 acc[NI][4];
#pragma unroll
  for (int i = 0; i < NI; ++i)
#pragma unroll
    for (int j = 0; j < 4; ++j) acc[i][j] = zero4;
  for (int k0 = 0; k0 < K; k0 += 64) {
    __syncthreads();  // prior iter's frag reads done
#pragma unroll
    for (int h = 0; h < 2; ++h) {
      int p = wave + 4 * h;  // wave covers planes {wave, wave+4}
#pragma unroll
      for (int j = 0; j < 2; ++j) {
        int row = j * 64 + lane;
        load_lds_16(A + (size_t)(n0 + row) * lda + k0 + p * 8,
                    As + p * PLANE128 + j * 1024 + lane * 16);
      }
      if constexpr (TALL) {
        load_lds_16(Bt + (size_t)(m0 + lane) * ldb + k0 + p * 8,
                    Bs + p * PLANE64 + lane * 16);
      } else {
#pragma unroll
        for (int j = 0; j < 2; ++j) {
          int row = j * 64 + lane;
          load_lds_16(Bt + (size_t)(m0 + row) * ldb + k0 + p * 8,
                      Bs + p * PLANE128 + j * 1024 + lane * 16);
        }
      }
    }
    __syncthreads();  // vmcnt drained -> staging visible
#pragma unroll
    for (int h = 0; h < 2; ++h) {
      int pb = h * 4 + quad;
      bf16x8 af[NI], bfr[4];
#pragma unroll
      for (int i = 0; i < NI; ++i) {
        int row = (TALL ? wave * 32 : wr * 64) + i * 16 + lrow;
        af[i] = *(const bf16x8*)(As + pb * PLANE128 + row * 16);
      }
#pragma unroll
      for (int j = 0; j < 4; ++j) {
        if constexpr (TALL)
          bfr[j] = *(const bf16x8*)(Bs + pb * PLANE64 + (j * 16 + lrow) * 16);
        else
          bfr[j] = *(const bf16x8*)(Bs + pb * PLANE128 +
                                    (wc * 64 + j * 16 + lrow) * 16);
      }
#pragma unroll
      for (int i = 0; i < NI; ++i)
#pragma unroll
        for (int j = 0; j < 4; ++j)
          acc[i][j] = mfma_bf16(af[i], bfr[j], acc[i][j]);
    }
  }
  float bv[4];
#pragma unroll
  for (int j = 0; j < 4; ++j) {
    int m = m0 + (TALL ? 0 : wc * 64) + j * 16 + lrow;
    bv[j] = (EPI == 5) ? 0.f : bias[m];
  }
#pragma unroll
  for (int i = 0; i < NI; ++i)
#pragma unroll
    for (int j = 0; j < 4; ++j)
#pragma unroll
      for (int r = 0; r < 4; ++r) {
        int n = n0 + (TALL ? wave * 32 : wr * 64) + i * 16 + quad * 4 + r;
        int m = m0 + (TALL ? 0 : wc * 64) + j * 16 + lrow;
        epi_store<EPI>(Cout, n, m, M, acc[i][j][r] + bv[j]);
      }
}

// ---- fused QKV: one dispatch over cast-bf16 {qx,kx,vx} --------------------
// grid (4, 192): seg = y>>6 selects input/weight/bias/out/epilogue. BK=64.
// Q out (seg0): [B,H,L,DK] pre-scaled by 0.125*log2e.
// K out (seg1): tiled [BH][L/64][dchunk=8][row=64][8]  (plane = d-chunk)
// V out (seg2): tiled [BH][L/64][kchunk=8][d=64][8]    (plane = k-chunk)
__global__ void __launch_bounds__(256) qkv_k(const bf16* __restrict__ xb,
                                             const bf16* __restrict__ wqT,
                                             const bf16* __restrict__ wkT,
                                             const bf16* __restrict__ wvT,
                                             const float* __restrict__ bq,
                                             const float* __restrict__ bk,
                                             const float* __restrict__ bv_,
                                             bf16* __restrict__ qh,
                                             bf16* __restrict__ kh,
                                             bf16* __restrict__ vt) {
  __shared__ __attribute__((aligned(16))) char As[8 * PLANE128];
  __shared__ __attribute__((aligned(16))) char Bs[8 * PLANE128];
  int tid = threadIdx.x, wave = tid >> 6, lane = tid & 63;
  int lrow = lane & 15, quad = lane >> 4;
  int seg = blockIdx.y >> 6;
  int n0 = (blockIdx.y & 63) * 128, m0 = blockIdx.x * 128;
  const bf16* Af = xb + ((size_t)seg << 22);
  const bf16* Bt = (seg == 0) ? wqT : (seg == 1) ? wkT : wvT;
  const float* bias = (seg == 0) ? bq : (seg == 1) ? bk : bv_;
  bf16* out = (seg == 0) ? qh : (seg == 1) ? kh : vt;
  int wr = wave >> 1, wc = wave & 1;
  floatx4 zero4 = {0.f, 0.f, 0.f, 0.f};
  floatx4 acc[4][4];
#pragma unroll
  for (int i = 0; i < 4; ++i)
#pragma unroll
    for (int j = 0; j < 4; ++j) acc[i][j] = zero4;
  for (int k0 = 0; k0 < 512; k0 += 64) {
    __syncthreads();
#pragma unroll
    for (int h = 0; h < 2; ++h) {
      int p = wave + 4 * h;
#pragma unroll
      for (int j = 0; j < 2; ++j) {
        int row = j * 64 + lane;
        load_lds_16(Af + (size_t)(n0 + row) * 512 + k0 + p * 8,
                    As + p * PLANE128 + j * 1024 + lane * 16);
        load_lds_16(Bt + (size_t)(m0 + row) * 512 + k0 + p * 8,
                    Bs + p * PLANE128 + j * 1024 + lane * 16);
      }
    }
    __syncthreads();
#pragma unroll
    for (int h = 0; h < 2; ++h) {
      int pb = h * 4 + quad;
      bf16x8 af[4], bfr[4];
#pragma unroll
      for (int t = 0; t < 4; ++t) {
        af[t] = *(const bf16x8*)(As + pb * PLANE128 + (wr * 64 + t * 16 + lrow) * 16);
        bfr[t] = *(const bf16x8*)(Bs + pb * PLANE128 + (wc * 64 + t * 16 + lrow) * 16);
      }
#pragma unroll
      for (int i = 0; i < 4; ++i)
#pragma unroll
        for (int j = 0; j < 4; ++j) acc[i][j] = mfma_bf16(af[i], bfr[j], acc[i][j]);
    }
  }
  float bvv[4];
#pragma unroll
  for (int j = 0; j < 4; ++j) bvv[j] = bias[m0 + wc * 64 + j * 16 + lrow];
  const float qscale = 0.1803368801f;  // 0.125 * log2(e), folded into Q
#pragma unroll
  for (int i = 0; i < 4; ++i)
#pragma unroll
    for (int j = 0; j < 4; ++j)
#pragma unroll
      for (int r = 0; r < 4; ++r) {
        int n = n0 + wr * 64 + i * 16 + quad * 4 + r;
        int m = m0 + wc * 64 + j * 16 + lrow;
        float val = acc[i][j][r] + bvv[j];
        int bb = n >> 11, l = n & 2047, hh = m >> 6, d = m & 63;
        if (seg == 0) {
          out[((size_t)((bb * 8 + hh) * 2048 + l)) * 64 + d] =
              (bf16)(val * qscale);
        } else {
          size_t tb_ = ((size_t)((bb * 8 + hh) * 32 + (l >> 6))) * 4096;
          if (seg == 1)
            out[tb_ + (d >> 3) * 512 + (l & 63) * 8 + (d & 7)] = (bf16)val;
          else
            out[tb_ + ((l >> 3) & 7) * 512 + d * 8 + (l & 7)] = (bf16)val;
        }
      }
}

// ---- flash attention v12: 8 waves, kv-split, tiled K/V staging ------------
// AMASK=1: mask via precomputed u32 AND-words (1 v_and per bf16 pair).
// AMASK=0: r11 bitmask fallback. Swapped QK^T, permlane P-redistribution,
// l via ones-MFMA, in-block (O,l) combine. Q pre-scaled in qkv_k.
template <bool AMASK>
__global__ void __launch_bounds__(512, 4) attn_k(const bf16* __restrict__ Qh,
                                                 const bf16* __restrict__ Kh,
                                                 const bf16* __restrict__ Vt,
                                                 const unsigned long long* __restrict__ MB,
                                                 const unsigned* __restrict__ MA,
                                                 bf16* __restrict__ Z) {
  __shared__ __attribute__((aligned(16))) char smem[8 * KVCH];
  int qt = blockIdx.x, h = blockIdx.y, b = blockIdx.z;
  int tid = threadIdx.x, wave = tid >> 6, lane = tid & 63;
  int hw = wave >> 2, wl = wave & 3;  // kv-half, local wave
  int lrow = lane & 15, quad = lane >> 4;
  int q0 = qt * 128;
  size_t headbase = (size_t)(b * 8 + h) * 2048 * 64;  // == (b*8+h)*32*4096

  bf16x8 qf[2][2];
#pragma unroll
  for (int u = 0; u < 2; ++u) {
    const bf16* Qp =
        Qh + headbase + (size_t)(q0 + wl * 32 + u * 16 + lrow) * 64 + quad * 8;
    qf[u][0] = *(const bf16x8*)Qp;
    qf[u][1] = *(const bf16x8*)(Qp + 32);
  }

  floatx4 zero4 = {0.f, 0.f, 0.f, 0.f};
  floatx4 o_acc[2][4], acc_l[2];
#pragma unroll
  for (int u = 0; u < 2; ++u) {
    acc_l[u] = zero4;
#pragma unroll
    for (int dt = 0; dt < 4; ++dt) o_acc[u][dt] = zero4;
  }
  bf16x8 ones;
#pragma unroll
  for (int j = 0; j < 8; ++j) ones[j] = (bf16)1.0f;

  const bf16* Kt0 = Kh + headbase;  // tiled: [32 tiles][4096]
  const bf16* Vt0 = Vt + headbase;
  // bitmask fallback pointers (lane owns q-rows {q0+wl*32+lrow, +16})
  const uint2* MB0 =
      (const uint2*)(MB + ((size_t)b * 2048 + q0 + wl * 32 + lrow) * 32);
  // AND-mask pointer: uint2 per (q-row, 4 k-pair block); row = 512 uint2
  const uint2* MAp =
      (const uint2*)(MA + ((size_t)(b * 2048 + q0 + wl * 32 + lrow)) * 1024);
  int sh = quad * 4;  // bit offset within 16-bit mask segment (fallback)

  char* KsH = smem + hw * 2 * KVCH;             // this half's K tiles [dbuf]
  char* VsH = smem + 4 * KVCH + hw * 2 * KVCH;  // this half's V tiles [dbuf]

  // stage tile kt into dbuf buf: 2 contiguous-1KB loads per wave per array
  auto stage = [&](int buf, int kt) {
    const bf16* Ktile = Kt0 + (size_t)kt * 4096;
    const bf16* Vtile = Vt0 + (size_t)kt * 4096;
#pragma unroll
    for (int j = 0; j < 2; ++j) {
      int p = wl * 2 + j;
      load_lds_16(Ktile + p * 512 + lane * 8,
                  KsH + buf * KVCH + p * PLANE64 + lane * 16);
      load_lds_16(Vtile + p * 512 + lane * 8,
                  VsH + buf * KVCH + p * PLANE64 + lane * 16);
    }
  };

  int ktbase = hw * 16;
  stage(0, ktbase);
  uint2 mwc[2], mwn[2];
  uint2 mac[2][4], man[2][4];
  if constexpr (AMASK) {
#pragma unroll
    for (int u = 0; u < 2; ++u)
#pragma unroll
      for (int nt = 0; nt < 4; ++nt)
        mac[u][nt] = MAp[u * 8192 + ktbase * 16 + nt * 4 + quad];
  } else {
    mwc[0] = MB0[ktbase];
    mwc[1] = MB0[512 + ktbase];
  }

  for (int it = 0; it < 16; ++it) {
    int kt = ktbase + it;
    int cur = it & 1;
    // drains: buf[cur] staging complete+visible; all waves' reads of
    // buf[cur^1] (from iter it-1) retired -> safe to overwrite it below.
    __syncthreads();
    if (it < 15) {
      stage(cur ^ 1, kt + 1);  // HBM/L2 latency hides under this it's compute
      if constexpr (AMASK) {
#pragma unroll
        for (int u = 0; u < 2; ++u)
#pragma unroll
          for (int nt = 0; nt < 4; ++nt)
            man[u][nt] = MAp[u * 8192 + (kt + 1) * 16 + nt * 4 + quad];
      } else {
        mwn[0] = MB0[kt + 1];
        mwn[1] = MB0[512 + kt + 1];
      }
    }
    const char* Kc = KsH + cur * KVCH;
    const char* Vc = VsH + cur * KVCH;
    unsigned S[2][4][2];  // [u][nt][pr] packed bf16x2 of masked exp scores
#pragma unroll
    for (int nt = 0; nt < 4; ++nt) {
      int R = nt * 16 + lrow;
      bf16x8 k0f = *(const bf16x8*)(Kc + quad * PLANE64 + R * 16);
      bf16x8 k1f = *(const bf16x8*)(Kc + (quad + 4) * PLANE64 + R * 16);
#pragma unroll
      for (int u = 0; u < 2; ++u) {
        floatx4 aa = zero4;
        aa = mfma_bf16(k0f, qf[u][0], aa);  // swapped: D[k_local][q] = S^T
        aa = mfma_bf16(k1f, qf[u][1], aa);
        if constexpr (AMASK) {
          float e0 = __builtin_amdgcn_exp2f(aa[0]);
          float e1 = __builtin_amdgcn_exp2f(aa[1]);
          float e2 = __builtin_amdgcn_exp2f(aa[2]);
          float e3 = __builtin_amdgcn_exp2f(aa[3]);
          S[u][nt][0] = pack2(e0, e1) & mac[u][nt].x;
          S[u][nt][1] = pack2(e2, e3) & mac[u][nt].y;
        } else {
          unsigned wn = ((nt & 2) ? mwc[u].y : mwc[u].x) >> ((nt & 1) * 16 + sh);
          float e[4];
#pragma unroll
          for (int r = 0; r < 4; ++r)
            e[r] = (wn & (1u << r)) ? __builtin_amdgcn_exp2f(aa[r]) : 0.f;
          S[u][nt][0] = pack2(e[0], e[1]);
          S[u][nt][1] = pack2(e[2], e[3]);
        }
      }
    }
    // V-frags read once, shared by both q-halves
    bf16x8 v0[4], v1[4];
#pragma unroll
    for (int dt = 0; dt < 4; ++dt) {
      int R = dt * 16 + lrow;
      v0[dt] = *(const bf16x8*)(Vc + quad * PLANE64 + R * 16);
      v1[dt] = *(const bf16x8*)(Vc + (quad + 4) * PLANE64 + R * 16);
    }
#pragma unroll
    for (int u = 0; u < 2; ++u) {
      // in-register redistribution: S[u][nt][pr] -> pf0/pf1 PV A-frags
      union { unsigned w[4]; bf16x8 v; } pf[2];
#pragma unroll
      for (int half = 0; half < 2; ++half)
#pragma unroll
        for (int pr = 0; pr < 2; ++pr) {
          uint2v a = __builtin_amdgcn_permlane32_swap(
              S[u][half * 2][pr], S[u][half * 2 + 1][pr], false, false);
          uint2v c = __builtin_amdgcn_permlane16_swap(a[0], a[1], false, false);
          pf[half].w[pr] = c[0];      // word pr   (k-offset 2*pr within 8)
          pf[half].w[pr + 2] = c[1];  // word pr+2 (k-offset 4+2*pr)
        }
      bf16x8 pf0 = pf[0].v, pf1 = pf[1].v;
      __builtin_amdgcn_s_setprio(1);
      acc_l[u] = mfma_bf16(pf0, ones, acc_l[u]);  // row sums -> l
      acc_l[u] = mfma_bf16(pf1, ones, acc_l[u]);
#pragma unroll
      for (int dt = 0; dt < 4; ++dt) {
        o_acc[u][dt] = mfma_bf16(pf0, v0[dt], o_acc[u][dt]);
        o_acc[u][dt] = mfma_bf16(pf1, v1[dt], o_acc[u][dt]);
      }
      __builtin_amdgcn_s_setprio(0);
    }
    if (it < 15) {
      if constexpr (AMASK) {
#pragma unroll
        for (int u = 0; u < 2; ++u)
#pragma unroll
          for (int nt = 0; nt < 4; ++nt) mac[u][nt] = man[u][nt];
      } else {
        mwc[0] = mwn[0];
        mwc[1] = mwn[1];
      }
    }
  }

  // ---- in-block combine: half1 dumps partials to LDS, half0 merges --------
  __syncthreads();  // all staging/frag LDS traffic done; smem reusable
  float* cb = (float*)smem;  // 256 lanes * 40 f32 = 40 KB
  int cbase = (wl * 64 + lane) * 40;
  if (hw == 1) {
#pragma unroll
    for (int u = 0; u < 2; ++u) {
#pragma unroll
      for (int dt = 0; dt < 4; ++dt)
        *(floatx4*)(cb + cbase + (u * 4 + dt) * 4) = o_acc[u][dt];
      *(floatx4*)(cb + cbase + 32 + u * 4) = acc_l[u];
    }
  }
  __syncthreads();
  if (hw == 0) {
#pragma unroll
    for (int u = 0; u < 2; ++u) {
#pragma unroll
      for (int dt = 0; dt < 4; ++dt)
        o_acc[u][dt] += *(const floatx4*)(cb + cbase + (u * 4 + dt) * 4);
      acc_l[u] += *(const floatx4*)(cb + cbase + 32 + u * 4);
    }
#pragma unroll
    for (int u = 0; u < 2; ++u) {
      float lr[4];
#pragma unroll
      for (int r = 0; r < 4; ++r) lr[r] = 1.0f / acc_l[u][r];
#pragma unroll
      for (int dt = 0; dt < 4; ++dt)
#pragma unroll
        for (int r = 0; r < 4; ++r) {
          int qrow = q0 + wl * 32 + u * 16 + quad * 4 + r;
          int d = dt * 16 + lrow;
          Z[((size_t)(b * 2048 + qrow)) * 512 + h * 64 + d] =
              (bf16)(o_acc[u][dt][r] * lr[r]);
        }
    }
  }
}

// ---- layernorm: out = LN(a + s_f32) * g + b -------------------------------
template <bool A_BF16, bool OUT_BF16>
__global__ void __launch_bounds__(256) ln_k(const void* __restrict__ a_,
                                            const float* __restrict__ s,
                                            const float* __restrict__ g,
                                            const float* __restrict__ bta,
                                            void* __restrict__ out_) {
  int row = blockIdx.x * 4 + (threadIdx.x >> 6);
  int lane = threadIdx.x & 63;
  size_t base = (size_t)row * 512 + lane * 8;
  float x[8];
  float4 sa = *(const float4*)(s + base);
  float4 sb = *(const float4*)(s + base + 4);
  if constexpr (A_BF16) {
    bf16x8 av = *(const bf16x8*)((const bf16*)a_ + base);
    x[0] = (float)av[0] + sa.x; x[1] = (float)av[1] + sa.y;
    x[2] = (float)av[2] + sa.z; x[3] = (float)av[3] + sa.w;
    x[4] = (float)av[4] + sb.x; x[5] = (float)av[5] + sb.y;
    x[6] = (float)av[6] + sb.z; x[7] = (float)av[7] + sb.w;
  } else {
    float4 a0 = *(const float4*)((const float*)a_ + base);
    float4 a1 = *(const float4*)((const float*)a_ + base + 4);
    x[0] = a0.x + sa.x; x[1] = a0.y + sa.y; x[2] = a0.z + sa.z; x[3] = a0.w + sa.w;
    x[4] = a1.x + sb.x; x[5] = a1.y + sb.y; x[6] = a1.z + sb.z; x[7] = a1.w + sb.w;
  }
  float sum = 0.f;
#pragma unroll
  for (int i = 0; i < 8; ++i) sum += x[i];
#pragma unroll
  for (int off = 1; off < 64; off <<= 1) sum += __shfl_xor(sum, off, 64);
  float mu = sum * (1.0f / 512.0f);
  float vs = 0.f;
#pragma unroll
  for (int i = 0; i < 8; ++i) { float d = x[i] - mu; vs += d * d; }
#pragma unroll
  for (int off = 1; off < 64; off <<= 1) vs += __shfl_xor(vs, off, 64);
  float rstd = rsqrtf(vs * (1.0f / 512.0f) + 1e-5f);
  float4 g0 = *(const float4*)(g + lane * 8);
  float4 g1 = *(const float4*)(g + lane * 8 + 4);
  float4 b0 = *(const float4*)(bta + lane * 8);
  float4 b1 = *(const float4*)(bta + lane * 8 + 4);
  float gg[8] = {g0.x, g0.y, g0.z, g0.w, g1.x, g1.y, g1.z, g1.w};
  float bb[8] = {b0.x, b0.y, b0.z, b0.w, b1.x, b1.y, b1.z, b1.w};
  if constexpr (OUT_BF16) {
    bf16x8 o;
#pragma unroll
    for (int i = 0; i < 8; ++i)
      o[i] = (bf16)((x[i] - mu) * rstd * gg[i] + bb[i]);
    *(bf16x8*)((bf16*)out_ + base) = o;
  } else {
    float4 o0, o1;
    o0.x = (x[0] - mu) * rstd * gg[0] + bb[0];
    o0.y = (x[1] - mu) * rstd * gg[1] + bb[1];
    o0.z = (x[2] - mu) * rstd * gg[2] + bb[2];
    o0.w = (x[3] - mu) * rstd * gg[3] + bb[3];
    o1.x = (x[4] - mu) * rstd * gg[4] + bb[4];
    o1.y = (x[5] - mu) * rstd * gg[5] + bb[5];
    o1.z = (x[6] - mu) * rstd * gg[6] + bb[6];
    o1.w = (x[7] - mu) * rstd * gg[7] + bb[7];
    *(float4*)((float*)out_ + base) = o0;
    *(float4*)((float*)out_ + base + 4) = o1;
  }
}

extern "C" void kernel_launch(void* const* d_in, const int* in_sizes, int n_in,
                              void* d_out, int out_size, void* d_ws, size_t ws_size,
                              hipStream_t stream) {
  const float* qx = (const float*)d_in[0];
  const float* kx = (const float*)d_in[1];
  const float* vx = (const float*)d_in[2];
  const int* maskPAD = (const int*)d_in[3];
  const float* wq = (const float*)d_in[4];
  const float* bq = (const float*)d_in[5];
  const float* wk = (const float*)d_in[6];
  const float* bk = (const float*)d_in[7];
  const float* wv = (const float*)d_in[8];
  const float* bv = (const float*)d_in[9];
  const float* wo = (const float*)d_in[10];
  const float* bo = (const float*)d_in[11];
  const float* w1 = (const float*)d_in[12];
  const float* b1 = (const float*)d_in[13];
  const float* w2 = (const float*)d_in[14];
  const float* b2 = (const float*)d_in[15];
  const float* g1 = (const float*)d_in[16];
  const float* be1 = (const float*)d_in[17];
  const float* g2 = (const float*)d_in[18];
  const float* be2 = (const float*)d_in[19];

  char* w = (char*)d_ws;
  size_t off = 0;
  auto alloc = [&](size_t bytes) {
    void* p = w + off;
    off += (bytes + 255) & ~(size_t)255;
    return p;
  };
  bf16* wqT = (bf16*)alloc(512 * 512 * 2);
  bf16* wkT = (bf16*)alloc(512 * 512 * 2);
  bf16* wvT = (bf16*)alloc(512 * 512 * 2);
  bf16* woT = (bf16*)alloc(512 * 512 * 2);
  bf16* w1T = (bf16*)alloc(2048 * 512 * 2);
  bf16* w2T = (bf16*)alloc(512 * 2048 * 2);
  unsigned long long* mbits = (unsigned long long*)alloc((size_t)4 * 2048 * 32 * 8);
  bf16* xb = (bf16*)alloc((size_t)3 * 4194304 * 2);  // cast qx,kx,vx
  bf16* qh = (bf16*)alloc((size_t)8192 * 512 * 2);
  bf16* kh = (bf16*)alloc((size_t)8192 * 512 * 2);
  bf16* vt = (bf16*)alloc((size_t)8192 * 512 * 2);
  bf16* z = (bf16*)alloc((size_t)8192 * 512 * 2);
  float* s12 = (float*)qh;  // over qh+kh (dead after attn)
  bf16* zn = vt;            // vt dead after attn
  size_t h1_bytes = (size_t)8192 * 2048 * 2;
  bool big = (off + h1_bytes) <= ws_size;
  bf16* h1 = big ? (bf16*)alloc(h1_bytes) : z;
  // AND-mask array (32MB): only if workspace allows
  size_t ma_bytes = (size_t)4 * 2048 * 1024 * 4;
  bool am = (off + ma_bytes) <= ws_size;
  unsigned* maskand = am ? (unsigned*)alloc(ma_bytes) : nullptr;

  dim3 tb(32, 8);
  transpose4_k<<<dim3(16, 16, 4), tb, 0, stream>>>(wq, wk, wv, wo, wqT, wkT, wvT, woT);
  transpose_k<<<dim3(64, 16), tb, 0, stream>>>(w1, w1T, 512, 2048);
  transpose_k<<<dim3(16, 64), tb, 0, stream>>>(w2, w2T, 2048, 512);
  if (am)
    maskand_k<<<8192, 256, 0, stream>>>(maskPAD, maskand);
  else
    maskbits_k<<<2048, 256, 0, stream>>>(maskPAD, mbits);
  cast3_k<<<6144, 256, 0, stream>>>(qx, kx, vx, xb);
  // fused QKV (768 blocks), bf16 A via global_load_lds
  qkv_k<<<dim3(4, 192), 256, 0, stream>>>(xb, wqT, wkT, wvT, bq, bk, bv,
                                          qh, kh, vt);
  // flash attention -> z (128 q-rows/block, 8 waves, kv-split, tiled K/V)
  if (am)
    attn_k<true><<<dim3(16, 8, 4), 512, 0, stream>>>(qh, kh, vt, mbits,
                                                     maskand, z);
  else
    attn_k<false><<<dim3(16, 8, 4), 512, 0, stream>>>(qh, kh, vt, mbits,
                                                      maskand, z);
  // out projection (TALL, 512 blocks) + LN1
  gemm_bt<4, true><<<dim3(8, 64), 256, 0, stream>>>(z, woT, bo, s12, 512, 512,
                                                    512, 512);
  ln_k<false, true><<<2048, 256, 0, stream>>>(vx, s12, g1, be1, zn);
  if (big) {
    gemm_bt<3, false><<<dim3(16, 64), 256, 0, stream>>>(zn, w1T, b1, h1, 2048,
                                                        512, 512, 512);
    gemm_bt<4, true><<<dim3(8, 64), 256, 0, stream>>>(h1, w2T, b2, s12, 512,
                                                      2048, 2048, 2048);
  } else {
    for (int p = 0; p < 4; ++p) {
      gemm_bt<3, true><<<dim3(8, 64), 256, 0, stream>>>(
          zn, w1T + (size_t)p * 512 * 512, b1 + p * 512, h1, 512, 512, 512, 512);
      if (p == 0)
        gemm_bt<4, true><<<dim3(8, 64), 256, 0, stream>>>(
            h1, w2T + p * 512, b2, s12, 512, 512, 512, 2048);
      else
        gemm_bt<5, true><<<dim3(8, 64), 256, 0, stream>>>(
            h1, w2T + p * 512, nullptr, s12, 512, 512, 512, 2048);
    }
  }
  ln_k<true, false><<<2048, 256, 0, stream>>>(zn, s12, g2, be2, (float*)d_out);
}

// Round 9
// 410.731 us; speedup vs baseline: 1.1598x; 1.1598x over previous
//
#include <hip/hip_runtime.h>
#include <cstdint>

// Transformer Post-LN block, MI355X gfx950.
// B=4, L=2048, FEA=512, H=8, DK=64, FFN=2048. f32 I/O, bf16 MFMA, f32 accum.
// Round 13: REVERT r12's AND-mask (32MB mask stream thrashed L2: attn 62->109,
// FETCH +26MB, WRITE +15MB). attn_k restored to r11's proven bitmask path
// (2MB, L2-resident). Forward change: 5 preprocessing dispatches (transpose4,
// 2x transpose, maskbits, cast3) merged into ONE 11264-block prep_k
// (saves 4 launch gaps). Tiled K/V staging + kv-split + permlane + swapped
// QK^T kept from r11. GEMM/LN kernels unchanged.

typedef __bf16 bf16;
typedef __bf16 bf16x8 __attribute__((ext_vector_type(8)));
typedef __bf16 bf16x2 __attribute__((ext_vector_type(2)));
typedef float floatx4 __attribute__((ext_vector_type(4)));
typedef unsigned uint2v __attribute__((ext_vector_type(2)));

__device__ __forceinline__ floatx4 mfma_bf16(bf16x8 a, bf16x8 b, floatx4 c) {
  return __builtin_amdgcn_mfma_f32_16x16x32_bf16(a, b, c, 0, 0, 0);
}

// async global->LDS, 16B/lane; LDS dest = wave-uniform base + lane*16.
__device__ __forceinline__ void load_lds_16(const void* g, void* l) {
  auto gp = reinterpret_cast<const void __attribute__((address_space(1)))*>(
      reinterpret_cast<uintptr_t>(g));
  auto lp = reinterpret_cast<void __attribute__((address_space(3)))*>(
      (unsigned int)reinterpret_cast<uintptr_t>(l));
  __builtin_amdgcn_global_load_lds(gp, lp, 16, 0, 0);
}

// pack two f32 -> u32 of 2 bf16 (compiler emits v_cvt_pk_bf16_f32)
__device__ __forceinline__ unsigned pack2(float a, float b) {
  bf16x2 p;
  p[0] = (bf16)a;
  p[1] = (bf16)b;
  return __builtin_bit_cast(unsigned, p);
}

// tanh-form GELU (max |err| ~1e-3, well under 0.0988 threshold)
__device__ __forceinline__ float gelu_f(float x) {
  float t = 0.7978845608f * (x + 0.044715f * x * x * x);
  float e = __builtin_amdgcn_exp2f(t * 2.885390082f);  // e^(2t)
  float th = 1.0f - 2.0f * __builtin_amdgcn_rcpf(e + 1.0f);
  return 0.5f * x * (1.0f + th);
}

// k-plane LDS geometry: plane = rows*16B, +16B pad between planes.
#define PLANE128 2064  // 128 rows * 16B + 16B pad
#define PLANE64 1040   // 64 rows * 16B + 16B pad
#define KVCH 8320      // 8 planes * PLANE64 (one K or V tile)

// ---- merged preprocessing: one dispatch, 11264 blocks ---------------------
// [0,1024):    transpose4 (wq,wk,wv,wo -> bf16 T)     grid was (16,16,4)
// [1024,2048): transpose w1 (K=512,M=2048)            grid was (64,16)
// [2048,3072): transpose w2 (K=2048,M=512)            grid was (16,64)
// [3072,5120): maskbits (2048 blocks)
// [5120,11264): cast3 qx,kx,vx -> bf16 (6144 blocks)
__global__ void __launch_bounds__(256) prep_k(
    const float* __restrict__ wq, const float* __restrict__ wk,
    const float* __restrict__ wv, const float* __restrict__ wo,
    bf16* __restrict__ wqT, bf16* __restrict__ wkT, bf16* __restrict__ wvT,
    bf16* __restrict__ woT, const float* __restrict__ w1,
    bf16* __restrict__ w1T, const float* __restrict__ w2,
    bf16* __restrict__ w2T, const int* __restrict__ mpad,
    unsigned long long* __restrict__ mbits, const float* __restrict__ qx,
    const float* __restrict__ kx, const float* __restrict__ vx,
    bf16* __restrict__ xb) {
  __shared__ float tile[32][33];
  int bid = blockIdx.x, tid = threadIdx.x;
  int tx = tid & 31, ty = tid >> 5;
  if (bid < 3072) {
    // transpose sections
    const float* in;
    bf16* out;
    int m0, k0, K, M;
    if (bid < 1024) {
      int z = bid >> 8, r = bid & 255;
      in = (z == 0) ? wq : (z == 1) ? wk : (z == 2) ? wv : wo;
      out = (z == 0) ? wqT : (z == 1) ? wkT : (z == 2) ? wvT : woT;
      m0 = (r & 15) * 32; k0 = (r >> 4) * 32; K = 512; M = 512;
    } else if (bid < 2048) {
      int r = bid - 1024;
      in = w1; out = w1T;
      m0 = (r & 63) * 32; k0 = (r >> 6) * 32; K = 512; M = 2048;
    } else {
      int r = bid - 2048;
      in = w2; out = w2T;
      m0 = (r & 15) * 32; k0 = (r >> 4) * 32; K = 2048; M = 512;
    }
    for (int i = ty; i < 32; i += 8)
      tile[i][tx] = in[(size_t)(k0 + i) * M + m0 + tx];
    __syncthreads();
    for (int i = ty; i < 32; i += 8)
      out[(size_t)(m0 + i) * K + k0 + tx] = (bf16)tile[tx][i];
  } else if (bid < 5120) {
    int r = bid - 3072;
    int w0 = r * 128 + (tid >> 6) * 32;
    int lane = tid & 63;
#pragma unroll 4
    for (int i = 0; i < 32; ++i) {
      int w = w0 + i;
      int v = mpad[(size_t)w * 64 + lane];
      unsigned long long bmask = __ballot(v != 0);
      if (lane == 0) mbits[w] = bmask;
    }
  } else {
    int r = bid - 5120;
    size_t idx = ((size_t)r * 256 + tid) * 8;
    int sel = (int)(idx >> 22);
    size_t off = idx & ((1u << 22) - 1);
    const float* src = (sel == 0) ? qx : (sel == 1) ? kx : vx;
    float4 a = *(const float4*)(src + off);
    float4 b = *(const float4*)(src + off + 4);
    bf16x8 o;
    o[0] = (bf16)a.x; o[1] = (bf16)a.y; o[2] = (bf16)a.z; o[3] = (bf16)a.w;
    o[4] = (bf16)b.x; o[5] = (bf16)b.y; o[6] = (bf16)b.z; o[7] = (bf16)b.w;
    *(bf16x8*)(xb + idx) = o;
  }
}

// ---- epilogue helper ------------------------------------------------------
template <int EPI>
__device__ __forceinline__ void epi_store(void* Cout, int n, int m, int M,
                                          float val) {
  if constexpr (EPI == 3) {  // GELU -> bf16
    ((bf16*)Cout)[(size_t)n * M + m] = (bf16)gelu_f(val);
  } else if constexpr (EPI == 4) {  // f32
    ((float*)Cout)[(size_t)n * M + m] = val;
  } else {  // f32 accumulate
    ((float*)Cout)[(size_t)n * M + m] += val;
  }
}

// ---- GEMM: C[N][M] = A[N][K] @ Bt[M][K]^T + bias, BK=64 -------------------
// WIDE: 128x128 tile, wave = 64x64 quadrant, acc 4x4.
// TALL: 128x64 tile, wave = 32 rows x 64 cols, acc 2x4. grid.x = M/64.
template <int EPI, bool TALL>
__global__ void __launch_bounds__(256) gemm_bt(const bf16* __restrict__ A,
                                               const bf16* __restrict__ Bt,
                                               const float* __restrict__ bias,
                                               void* __restrict__ Cout,
                                               int M, int K, int lda, int ldb) {
  __shared__ __attribute__((aligned(16))) char As[8 * PLANE128];
  __shared__ __attribute__((aligned(16))) char Bs[TALL ? 8 * PLANE64 : 8 * PLANE128];
  int tid = threadIdx.x, wave = tid >> 6, lane = tid & 63;
  int lrow = lane & 15, quad = lane >> 4;
  int n0 = blockIdx.y * 128;
  int m0 = blockIdx.x * (TALL ? 64 : 128);
  int wr = wave >> 1, wc = wave & 1;  // WIDE quadrant
  floatx4 zero4 = {0.f, 0.f, 0.f, 0.f};
  constexpr int NI = TALL ? 2 : 4;
  floatx4 acc[NI][4];
#pragma unroll
  for (int i = 0; i < NI; ++i)
#pragma unroll
    for (int j = 0; j < 4; ++j) acc[i][j] = zero4;
  for (int k0 = 0; k0 < K; k0 += 64) {
    __syncthreads();  // prior iter's frag reads done
#pragma unroll
    for (int h = 0; h < 2; ++h) {
      int p = wave + 4 * h;  // wave covers planes {wave, wave+4}
#pragma unroll
      for (int j = 0; j < 2; ++j) {
        int row = j * 64 + lane;
        load_lds_16(A + (size_t)(n0 + row) * lda + k0 + p * 8,
                    As + p * PLANE128 + j * 1024 + lane * 16);
      }
      if constexpr (TALL) {
        load_lds_16(Bt + (size_t)(m0 + lane) * ldb + k0 + p * 8,
                    Bs + p * PLANE64 + lane * 16);
      } else {
#pragma unroll
        for (int j = 0; j < 2; ++j) {
          int row = j * 64 + lane;
          load_lds_16(Bt + (size_t)(m0 + row) * ldb + k0 + p * 8,
                      Bs + p * PLANE128 + j * 1024 + lane * 16);
        }
      }
    }
    __syncthreads();  // vmcnt drained -> staging visible
#pragma unroll
    for (int h = 0; h < 2; ++h) {
      int pb = h * 4 + quad;
      bf16x8 af[NI], bfr[4];
#pragma unroll
      for (int i = 0; i < NI; ++i) {
        int row = (TALL ? wave * 32 : wr * 64) + i * 16 + lrow;
        af[i] = *(const bf16x8*)(As + pb * PLANE128 + row * 16);
      }
#pragma unroll
      for (int j = 0; j < 4; ++j) {
        if constexpr (TALL)
          bfr[j] = *(const bf16x8*)(Bs + pb * PLANE64 + (j * 16 + lrow) * 16);
        else
          bfr[j] = *(const bf16x8*)(Bs + pb * PLANE128 +
                                    (wc * 64 + j * 16 + lrow) * 16);
      }
#pragma unroll
      for (int i = 0; i < NI; ++i)
#pragma unroll
        for (int j = 0; j < 4; ++j)
          acc[i][j] = mfma_bf16(af[i], bfr[j], acc[i][j]);
    }
  }
  float bv[4];
#pragma unroll
  for (int j = 0; j < 4; ++j) {
    int m = m0 + (TALL ? 0 : wc * 64) + j * 16 + lrow;
    bv[j] = (EPI == 5) ? 0.f : bias[m];
  }
#pragma unroll
  for (int i = 0; i < NI; ++i)
#pragma unroll
    for (int j = 0; j < 4; ++j)
#pragma unroll
      for (int r = 0; r < 4; ++r) {
        int n = n0 + (TALL ? wave * 32 : wr * 64) + i * 16 + quad * 4 + r;
        int m = m0 + (TALL ? 0 : wc * 64) + j * 16 + lrow;
        epi_store<EPI>(Cout, n, m, M, acc[i][j][r] + bv[j]);
      }
}

// ---- fused QKV: one dispatch over cast-bf16 {qx,kx,vx} --------------------
// grid (4, 192): seg = y>>6 selects input/weight/bias/out/epilogue. BK=64.
// Q out (seg0): [B,H,L,DK] pre-scaled by 0.125*log2e.
// K out (seg1): tiled [BH][L/64][dchunk=8][row=64][8]  (plane = d-chunk)
// V out (seg2): tiled [BH][L/64][kchunk=8][d=64][8]    (plane = k-chunk)
__global__ void __launch_bounds__(256) qkv_k(const bf16* __restrict__ xb,
                                             const bf16* __restrict__ wqT,
                                             const bf16* __restrict__ wkT,
                                             const bf16* __restrict__ wvT,
                                             const float* __restrict__ bq,
                                             const float* __restrict__ bk,
                                             const float* __restrict__ bv_,
                                             bf16* __restrict__ qh,
                                             bf16* __restrict__ kh,
                                             bf16* __restrict__ vt) {
  __shared__ __attribute__((aligned(16))) char As[8 * PLANE128];
  __shared__ __attribute__((aligned(16))) char Bs[8 * PLANE128];
  int tid = threadIdx.x, wave = tid >> 6, lane = tid & 63;
  int lrow = lane & 15, quad = lane >> 4;
  int seg = blockIdx.y >> 6;
  int n0 = (blockIdx.y & 63) * 128, m0 = blockIdx.x * 128;
  const bf16* Af = xb + ((size_t)seg << 22);
  const bf16* Bt = (seg == 0) ? wqT : (seg == 1) ? wkT : wvT;
  const float* bias = (seg == 0) ? bq : (seg == 1) ? bk : bv_;
  bf16* out = (seg == 0) ? qh : (seg == 1) ? kh : vt;
  int wr = wave >> 1, wc = wave & 1;
  floatx4 zero4 = {0.f, 0.f, 0.f, 0.f};
  floatx4 acc[4][4];
#pragma unroll
  for (int i = 0; i < 4; ++i)
#pragma unroll
    for (int j = 0; j < 4; ++j) acc[i][j] = zero4;
  for (int k0 = 0; k0 < 512; k0 += 64) {
    __syncthreads();
#pragma unroll
    for (int h = 0; h < 2; ++h) {
      int p = wave + 4 * h;
#pragma unroll
      for (int j = 0; j < 2; ++j) {
        int row = j * 64 + lane;
        load_lds_16(Af + (size_t)(n0 + row) * 512 + k0 + p * 8,
                    As + p * PLANE128 + j * 1024 + lane * 16);
        load_lds_16(Bt + (size_t)(m0 + row) * 512 + k0 + p * 8,
                    Bs + p * PLANE128 + j * 1024 + lane * 16);
      }
    }
    __syncthreads();
#pragma unroll
    for (int h = 0; h < 2; ++h) {
      int pb = h * 4 + quad;
      bf16x8 af[4], bfr[4];
#pragma unroll
      for (int t = 0; t < 4; ++t) {
        af[t] = *(const bf16x8*)(As + pb * PLANE128 + (wr * 64 + t * 16 + lrow) * 16);
        bfr[t] = *(const bf16x8*)(Bs + pb * PLANE128 + (wc * 64 + t * 16 + lrow) * 16);
      }
#pragma unroll
      for (int i = 0; i < 4; ++i)
#pragma unroll
        for (int j = 0; j < 4; ++j) acc[i][j] = mfma_bf16(af[i], bfr[j], acc[i][j]);
    }
  }
  float bvv[4];
#pragma unroll
  for (int j = 0; j < 4; ++j) bvv[j] = bias[m0 + wc * 64 + j * 16 + lrow];
  const float qscale = 0.1803368801f;  // 0.125 * log2(e), folded into Q
#pragma unroll
  for (int i = 0; i < 4; ++i)
#pragma unroll
    for (int j = 0; j < 4; ++j)
#pragma unroll
      for (int r = 0; r < 4; ++r) {
        int n = n0 + wr * 64 + i * 16 + quad * 4 + r;
        int m = m0 + wc * 64 + j * 16 + lrow;
        float val = acc[i][j][r] + bvv[j];
        int bb = n >> 11, l = n & 2047, hh = m >> 6, d = m & 63;
        if (seg == 0) {
          out[((size_t)((bb * 8 + hh) * 2048 + l)) * 64 + d] =
              (bf16)(val * qscale);
        } else {
          size_t tb_ = ((size_t)((bb * 8 + hh) * 32 + (l >> 6))) * 4096;
          if (seg == 1)
            out[tb_ + (d >> 3) * 512 + (l & 63) * 8 + (d & 7)] = (bf16)val;
          else
            out[tb_ + ((l >> 3) & 7) * 512 + d * 8 + (l & 7)] = (bf16)val;
        }
      }
}

// ---- flash attention (r11-proven): 8 waves, kv-split, tiled K/V staging ---
// waves 0-3 (hw=0): kt 0..15; waves 4-7 (hw=1): kt 16..31. Each half has its
// own dbuf K/V LDS stream; every global_load_lds reads contiguous 1KB from
// the tiled K/V layouts. QI=2, swapped QK^T, permlane P-redistribution,
// l via ones-MFMA, in-block (O,l) combine. Q pre-scaled in qkv_k.
__global__ void __launch_bounds__(512, 4) attn_k(const bf16* __restrict__ Qh,
                                                 const bf16* __restrict__ Kh,
                                                 const bf16* __restrict__ Vt,
                                                 const unsigned long long* __restrict__ MB,
                                                 bf16* __restrict__ Z) {
  __shared__ __attribute__((aligned(16))) char smem[8 * KVCH];
  int qt = blockIdx.x, h = blockIdx.y, b = blockIdx.z;
  int tid = threadIdx.x, wave = tid >> 6, lane = tid & 63;
  int hw = wave >> 2, wl = wave & 3;  // kv-half, local wave
  int lrow = lane & 15, quad = lane >> 4;
  int q0 = qt * 128;
  size_t headbase = (size_t)(b * 8 + h) * 2048 * 64;  // == (b*8+h)*32*4096

  bf16x8 qf[2][2];
#pragma unroll
  for (int u = 0; u < 2; ++u) {
    const bf16* Qp =
        Qh + headbase + (size_t)(q0 + wl * 32 + u * 16 + lrow) * 64 + quad * 8;
    qf[u][0] = *(const bf16x8*)Qp;
    qf[u][1] = *(const bf16x8*)(Qp + 32);
  }

  floatx4 zero4 = {0.f, 0.f, 0.f, 0.f};
  floatx4 o_acc[2][4], acc_l[2];
#pragma unroll
  for (int u = 0; u < 2; ++u) {
    acc_l[u] = zero4;
#pragma unroll
    for (int dt = 0; dt < 4; ++dt) o_acc[u][dt] = zero4;
  }
  bf16x8 ones;
#pragma unroll
  for (int j = 0; j < 8; ++j) ones[j] = (bf16)1.0f;

  const bf16* Kt0 = Kh + headbase;  // tiled: [32 tiles][4096]
  const bf16* Vt0 = Vt + headbase;
  // lane owns q-rows {q0+wl*32+lrow, +16}: one mask word per u per kt
  const uint2* MB0 =
      (const uint2*)(MB + ((size_t)b * 2048 + q0 + wl * 32 + lrow) * 32);
  int sh = quad * 4;  // bit offset within 16-bit mask segment

  char* KsH = smem + hw * 2 * KVCH;             // this half's K tiles [dbuf]
  char* VsH = smem + 4 * KVCH + hw * 2 * KVCH;  // this half's V tiles [dbuf]

  // stage tile kt into dbuf buf: 2 contiguous-1KB loads per wave per array
  auto stage = [&](int buf, int kt) {
    const bf16* Ktile = Kt0 + (size_t)kt * 4096;
    const bf16* Vtile = Vt0 + (size_t)kt * 4096;
#pragma unroll
    for (int j = 0; j < 2; ++j) {
      int p = wl * 2 + j;
      load_lds_16(Ktile + p * 512 + lane * 8,
                  KsH + buf * KVCH + p * PLANE64 + lane * 16);
      load_lds_16(Vtile + p * 512 + lane * 8,
                  VsH + buf * KVCH + p * PLANE64 + lane * 16);
    }
  };

  int ktbase = hw * 16;
  stage(0, ktbase);
  uint2 mwc[2] = {MB0[ktbase], MB0[512 + ktbase]};

  for (int it = 0; it < 16; ++it) {
    int kt = ktbase + it;
    int cur = it & 1;
    // drains: buf[cur] staging complete+visible; all waves' reads of
    // buf[cur^1] (from iter it-1) retired -> safe to overwrite it below.
    __syncthreads();
    uint2 mwn[2];
    if (it < 15) {
      stage(cur ^ 1, kt + 1);  // HBM/L2 latency hides under this it's compute
      mwn[0] = MB0[kt + 1];
      mwn[1] = MB0[512 + kt + 1];
    }
    const char* Kc = KsH + cur * KVCH;
    const char* Vc = VsH + cur * KVCH;
    unsigned S[2][4][2];  // [u][nt][pr] packed bf16x2 of masked exp scores
#pragma unroll
    for (int nt = 0; nt < 4; ++nt) {
      int R = nt * 16 + lrow;
      bf16x8 k0f = *(const bf16x8*)(Kc + quad * PLANE64 + R * 16);
      bf16x8 k1f = *(const bf16x8*)(Kc + (quad + 4) * PLANE64 + R * 16);
#pragma unroll
      for (int u = 0; u < 2; ++u) {
        floatx4 aa = zero4;
        aa = mfma_bf16(k0f, qf[u][0], aa);  // swapped: D[k_local][q] = S^T
        aa = mfma_bf16(k1f, qf[u][1], aa);
        unsigned wn = ((nt & 2) ? mwc[u].y : mwc[u].x) >> ((nt & 1) * 16 + sh);
        float e[4];
#pragma unroll
        for (int r = 0; r < 4; ++r)
          e[r] = (wn & (1u << r)) ? __builtin_amdgcn_exp2f(aa[r]) : 0.f;
        S[u][nt][0] = pack2(e[0], e[1]);
        S[u][nt][1] = pack2(e[2], e[3]);
      }
    }
    // V-frags read once, shared by both q-halves
    bf16x8 v0[4], v1[4];
#pragma unroll
    for (int dt = 0; dt < 4; ++dt) {
      int R = dt * 16 + lrow;
      v0[dt] = *(const bf16x8*)(Vc + quad * PLANE64 + R * 16);
      v1[dt] = *(const bf16x8*)(Vc + (quad + 4) * PLANE64 + R * 16);
    }
#pragma unroll
    for (int u = 0; u < 2; ++u) {
      // in-register redistribution: S[u][nt][pr] -> pf0/pf1 PV A-frags
      union { unsigned w[4]; bf16x8 v; } pf[2];
#pragma unroll
      for (int half = 0; half < 2; ++half)
#pragma unroll
        for (int pr = 0; pr < 2; ++pr) {
          uint2v a = __builtin_amdgcn_permlane32_swap(
              S[u][half * 2][pr], S[u][half * 2 + 1][pr], false, false);
          uint2v c = __builtin_amdgcn_permlane16_swap(a[0], a[1], false, false);
          pf[half].w[pr] = c[0];      // word pr   (k-offset 2*pr within 8)
          pf[half].w[pr + 2] = c[1];  // word pr+2 (k-offset 4+2*pr)
        }
      bf16x8 pf0 = pf[0].v, pf1 = pf[1].v;
      __builtin_amdgcn_s_setprio(1);
      acc_l[u] = mfma_bf16(pf0, ones, acc_l[u]);  // row sums -> l
      acc_l[u] = mfma_bf16(pf1, ones, acc_l[u]);
#pragma unroll
      for (int dt = 0; dt < 4; ++dt) {
        o_acc[u][dt] = mfma_bf16(pf0, v0[dt], o_acc[u][dt]);
        o_acc[u][dt] = mfma_bf16(pf1, v1[dt], o_acc[u][dt]);
      }
      __builtin_amdgcn_s_setprio(0);
    }
    if (it < 15) { mwc[0] = mwn[0]; mwc[1] = mwn[1]; }
  }

  // ---- in-block combine: half1 dumps partials to LDS, half0 merges --------
  __syncthreads();  // all staging/frag LDS traffic done; smem reusable
  float* cb = (float*)smem;  // 256 lanes * 40 f32 = 40 KB
  int cbase = (wl * 64 + lane) * 40;
  if (hw == 1) {
#pragma unroll
    for (int u = 0; u < 2; ++u) {
#pragma unroll
      for (int dt = 0; dt < 4; ++dt)
        *(floatx4*)(cb + cbase + (u * 4 + dt) * 4) = o_acc[u][dt];
      *(floatx4*)(cb + cbase + 32 + u * 4) = acc_l[u];
    }
  }
  __syncthreads();
  if (hw == 0) {
#pragma unroll
    for (int u = 0; u < 2; ++u) {
#pragma unroll
      for (int dt = 0; dt < 4; ++dt)
        o_acc[u][dt] += *(const floatx4*)(cb + cbase + (u * 4 + dt) * 4);
      acc_l[u] += *(const floatx4*)(cb + cbase + 32 + u * 4);
    }
#pragma unroll
    for (int u = 0; u < 2; ++u) {
      float lr[4];
#pragma unroll
      for (int r = 0; r < 4; ++r) lr[r] = 1.0f / acc_l[u][r];
#pragma unroll
      for (int dt = 0; dt < 4; ++dt)
#pragma unroll
        for (int r = 0; r < 4; ++r) {
          int qrow = q0 + wl * 32 + u * 16 + quad * 4 + r;
          int d = dt * 16 + lrow;
          Z[((size_t)(b * 2048 + qrow)) * 512 + h * 64 + d] =
              (bf16)(o_acc[u][dt][r] * lr[r]);
        }
    }
  }
}

// ---- layernorm: out = LN(a + s_f32) * g + b -------------------------------
template <bool A_BF16, bool OUT_BF16>
__global__ void __launch_bounds__(256) ln_k(const void* __restrict__ a_,
                                            const float* __restrict__ s,
                                            const float* __restrict__ g,
                                            const float* __restrict__ bta,
                                            void* __restrict__ out_) {
  int row = blockIdx.x * 4 + (threadIdx.x >> 6);
  int lane = threadIdx.x & 63;
  size_t base = (size_t)row * 512 + lane * 8;
  float x[8];
  float4 sa = *(const float4*)(s + base);
  float4 sb = *(const float4*)(s + base + 4);
  if constexpr (A_BF16) {
    bf16x8 av = *(const bf16x8*)((const bf16*)a_ + base);
    x[0] = (float)av[0] + sa.x; x[1] = (float)av[1] + sa.y;
    x[2] = (float)av[2] + sa.z; x[3] = (float)av[3] + sa.w;
    x[4] = (float)av[4] + sb.x; x[5] = (float)av[5] + sb.y;
    x[6] = (float)av[6] + sb.z; x[7] = (float)av[7] + sb.w;
  } else {
    float4 a0 = *(const float4*)((const float*)a_ + base);
    float4 a1 = *(const float4*)((const float*)a_ + base + 4);
    x[0] = a0.x + sa.x; x[1] = a0.y + sa.y; x[2] = a0.z + sa.z; x[3] = a0.w + sa.w;
    x[4] = a1.x + sb.x; x[5] = a1.y + sb.y; x[6] = a1.z + sb.z; x[7] = a1.w + sb.w;
  }
  float sum = 0.f;
#pragma unroll
  for (int i = 0; i < 8; ++i) sum += x[i];
#pragma unroll
  for (int off = 1; off < 64; off <<= 1) sum += __shfl_xor(sum, off, 64);
  float mu = sum * (1.0f / 512.0f);
  float vs = 0.f;
#pragma unroll
  for (int i = 0; i < 8; ++i) { float d = x[i] - mu; vs += d * d; }
#pragma unroll
  for (int off = 1; off < 64; off <<= 1) vs += __shfl_xor(vs, off, 64);
  float rstd = rsqrtf(vs * (1.0f / 512.0f) + 1e-5f);
  float4 g0 = *(const float4*)(g + lane * 8);
  float4 g1 = *(const float4*)(g + lane * 8 + 4);
  float4 b0 = *(const float4*)(bta + lane * 8);
  float4 b1 = *(const float4*)(bta + lane * 8 + 4);
  float gg[8] = {g0.x, g0.y, g0.z, g0.w, g1.x, g1.y, g1.z, g1.w};
  float bb[8] = {b0.x, b0.y, b0.z, b0.w, b1.x, b1.y, b1.z, b1.w};
  if constexpr (OUT_BF16) {
    bf16x8 o;
#pragma unroll
    for (int i = 0; i < 8; ++i)
      o[i] = (bf16)((x[i] - mu) * rstd * gg[i] + bb[i]);
    *(bf16x8*)((bf16*)out_ + base) = o;
  } else {
    float4 o0, o1;
    o0.x = (x[0] - mu) * rstd * gg[0] + bb[0];
    o0.y = (x[1] - mu) * rstd * gg[1] + bb[1];
    o0.z = (x[2] - mu) * rstd * gg[2] + bb[2];
    o0.w = (x[3] - mu) * rstd * gg[3] + bb[3];
    o1.x = (x[4] - mu) * rstd * gg[4] + bb[4];
    o1.y = (x[5] - mu) * rstd * gg[5] + bb[5];
    o1.z = (x[6] - mu) * rstd * gg[6] + bb[6];
    o1.w = (x[7] - mu) * rstd * gg[7] + bb[7];
    *(float4*)((float*)out_ + base) = o0;
    *(float4*)((float*)out_ + base + 4) = o1;
  }
}

extern "C" void kernel_launch(void* const* d_in, const int* in_sizes, int n_in,
                              void* d_out, int out_size, void* d_ws, size_t ws_size,
                              hipStream_t stream) {
  const float* qx = (const float*)d_in[0];
  const float* kx = (const float*)d_in[1];
  const float* vx = (const float*)d_in[2];
  const int* maskPAD = (const int*)d_in[3];
  const float* wq = (const float*)d_in[4];
  const float* bq = (const float*)d_in[5];
  const float* wk = (const float*)d_in[6];
  const float* bk = (const float*)d_in[7];
  const float* wv = (const float*)d_in[8];
  const float* bv = (const float*)d_in[9];
  const float* wo = (const float*)d_in[10];
  const float* bo = (const float*)d_in[11];
  const float* w1 = (const float*)d_in[12];
  const float* b1 = (const float*)d_in[13];
  const float* w2 = (const float*)d_in[14];
  const float* b2 = (const float*)d_in[15];
  const float* g1 = (const float*)d_in[16];
  const float* be1 = (const float*)d_in[17];
  const float* g2 = (const float*)d_in[18];
  const float* be2 = (const float*)d_in[19];

  char* w = (char*)d_ws;
  size_t off = 0;
  auto alloc = [&](size_t bytes) {
    void* p = w + off;
    off += (bytes + 255) & ~(size_t)255;
    return p;
  };
  bf16* wqT = (bf16*)alloc(512 * 512 * 2);
  bf16* wkT = (bf16*)alloc(512 * 512 * 2);
  bf16* wvT = (bf16*)alloc(512 * 512 * 2);
  bf16* woT = (bf16*)alloc(512 * 512 * 2);
  bf16* w1T = (bf16*)alloc(2048 * 512 * 2);
  bf16* w2T = (bf16*)alloc(512 * 2048 * 2);
  unsigned long long* mbits = (unsigned long long*)alloc((size_t)4 * 2048 * 32 * 8);
  bf16* xb = (bf16*)alloc((size_t)3 * 4194304 * 2);  // cast qx,kx,vx
  bf16* qh = (bf16*)alloc((size_t)8192 * 512 * 2);
  bf16* kh = (bf16*)alloc((size_t)8192 * 512 * 2);
  bf16* vt = (bf16*)alloc((size_t)8192 * 512 * 2);
  bf16* z = (bf16*)alloc((size_t)8192 * 512 * 2);
  float* s12 = (float*)qh;  // over qh+kh (dead after attn)
  bf16* zn = vt;            // vt dead after attn
  size_t h1_bytes = (size_t)8192 * 2048 * 2;
  bool big = (off + h1_bytes) <= ws_size;
  bf16* h1 = big ? (bf16*)alloc(h1_bytes) : z;

  // merged preprocessing: transposes + maskbits + cast3, one dispatch
  prep_k<<<11264, 256, 0, stream>>>(wq, wk, wv, wo, wqT, wkT, wvT, woT, w1, w1T,
                                    w2, w2T, maskPAD, mbits, qx, kx, vx, xb);
  // fused QKV (768 blocks), bf16 A via global_load_lds
  qkv_k<<<dim3(4, 192), 256, 0, stream>>>(xb, wqT, wkT, wvT, bq, bk, bv,
                                          qh, kh, vt);
  // flash attention -> z (128 q-rows/block, 8 waves, kv-split, tiled K/V)
  attn_k<<<dim3(16, 8, 4), 512, 0, stream>>>(qh, kh, vt, mbits, z);
  // out projection (TALL, 512 blocks) + LN1
  gemm_bt<4, true><<<dim3(8, 64), 256, 0, stream>>>(z, woT, bo, s12, 512, 512,
                                                    512, 512);
  ln_k<false, true><<<2048, 256, 0, stream>>>(vx, s12, g1, be1, zn);
  if (big) {
    gemm_bt<3, false><<<dim3(16, 64), 256, 0, stream>>>(zn, w1T, b1, h1, 2048,
                                                        512, 512, 512);
    gemm_bt<4, true><<<dim3(8, 64), 256, 0, stream>>>(h1, w2T, b2, s12, 512,
                                                      2048, 2048, 2048);
  } else {
    for (int p = 0; p < 4; ++p) {
      gemm_bt<3, true><<<dim3(8, 64), 256, 0, stream>>>(
          zn, w1T + (size_t)p * 512 * 512, b1 + p * 512, h1, 512, 512, 512, 512);
      if (p == 0)
        gemm_bt<4, true><<<dim3(8, 64), 256, 0, stream>>>(
            h1, w2T + p * 512, b2, s12, 512, 512, 512, 2048);
      else
        gemm_bt<5, true><<<dim3(8, 64), 256, 0, stream>>>(
            h1, w2T + p * 512, nullptr, s12, 512, 512, 512, 2048);
    }
  }
  ln_k<true, false><<<2048, 256, 0, stream>>>(zn, s12, g2, be2, (float*)d_out);
}

// Round 10
// 403.183 us; speedup vs baseline: 1.1816x; 1.0187x over previous
//
#include <hip/hip_runtime.h>
#include <cstdint>

// Transformer Post-LN block, MI355X gfx950.
// B=4, L=2048, FEA=512, H=8, DK=64, FFN=2048. f32 I/O, bf16 MFMA, f32 accum.
// Round 14: GEMM staging restructure — gemm_bt (WIDE/TALL) and qkv_k moved
// from serial {barrier, stage, drain-barrier, compute} to the attn-proven
// {barrier, prefetch next, compute current} double-buffer with BK=32:
// per-buffer LDS halves so TOTAL LDS (and occupancy) is unchanged, barrier
// count unchanged, but staging latency now hides under compute. Frag reads
// simplify to plane=quad. attn/prep/LN unchanged from r13 (410.7 us).

typedef __bf16 bf16;
typedef __bf16 bf16x8 __attribute__((ext_vector_type(8)));
typedef __bf16 bf16x2 __attribute__((ext_vector_type(2)));
typedef float floatx4 __attribute__((ext_vector_type(4)));
typedef unsigned uint2v __attribute__((ext_vector_type(2)));

__device__ __forceinline__ floatx4 mfma_bf16(bf16x8 a, bf16x8 b, floatx4 c) {
  return __builtin_amdgcn_mfma_f32_16x16x32_bf16(a, b, c, 0, 0, 0);
}

// async global->LDS, 16B/lane; LDS dest = wave-uniform base + lane*16.
__device__ __forceinline__ void load_lds_16(const void* g, void* l) {
  auto gp = reinterpret_cast<const void __attribute__((address_space(1)))*>(
      reinterpret_cast<uintptr_t>(g));
  auto lp = reinterpret_cast<void __attribute__((address_space(3)))*>(
      (unsigned int)reinterpret_cast<uintptr_t>(l));
  __builtin_amdgcn_global_load_lds(gp, lp, 16, 0, 0);
}

// pack two f32 -> u32 of 2 bf16 (compiler emits v_cvt_pk_bf16_f32)
__device__ __forceinline__ unsigned pack2(float a, float b) {
  bf16x2 p;
  p[0] = (bf16)a;
  p[1] = (bf16)b;
  return __builtin_bit_cast(unsigned, p);
}

// tanh-form GELU (max |err| ~1e-3, well under 0.0988 threshold)
__device__ __forceinline__ float gelu_f(float x) {
  float t = 0.7978845608f * (x + 0.044715f * x * x * x);
  float e = __builtin_amdgcn_exp2f(t * 2.885390082f);  // e^(2t)
  float th = 1.0f - 2.0f * __builtin_amdgcn_rcpf(e + 1.0f);
  return 0.5f * x * (1.0f + th);
}

// k-plane LDS geometry: plane = rows*16B, +16B pad between planes.
#define PLANE128 2064  // 128 rows * 16B + 16B pad
#define PLANE64 1040   // 64 rows * 16B + 16B pad
#define KVCH 8320      // 8 planes * PLANE64 (one K or V tile)

// ---- merged preprocessing: one dispatch, 11264 blocks ---------------------
// [0,1024):    transpose4 (wq,wk,wv,wo -> bf16 T)
// [1024,2048): transpose w1 (K=512,M=2048)
// [2048,3072): transpose w2 (K=2048,M=512)
// [3072,5120): maskbits (2048 blocks)
// [5120,11264): cast3 qx,kx,vx -> bf16 (6144 blocks)
__global__ void __launch_bounds__(256) prep_k(
    const float* __restrict__ wq, const float* __restrict__ wk,
    const float* __restrict__ wv, const float* __restrict__ wo,
    bf16* __restrict__ wqT, bf16* __restrict__ wkT, bf16* __restrict__ wvT,
    bf16* __restrict__ woT, const float* __restrict__ w1,
    bf16* __restrict__ w1T, const float* __restrict__ w2,
    bf16* __restrict__ w2T, const int* __restrict__ mpad,
    unsigned long long* __restrict__ mbits, const float* __restrict__ qx,
    const float* __restrict__ kx, const float* __restrict__ vx,
    bf16* __restrict__ xb) {
  __shared__ float tile[32][33];
  int bid = blockIdx.x, tid = threadIdx.x;
  int tx = tid & 31, ty = tid >> 5;
  if (bid < 3072) {
    const float* in;
    bf16* out;
    int m0, k0, K, M;
    if (bid < 1024) {
      int z = bid >> 8, r = bid & 255;
      in = (z == 0) ? wq : (z == 1) ? wk : (z == 2) ? wv : wo;
      out = (z == 0) ? wqT : (z == 1) ? wkT : (z == 2) ? wvT : woT;
      m0 = (r & 15) * 32; k0 = (r >> 4) * 32; K = 512; M = 512;
    } else if (bid < 2048) {
      int r = bid - 1024;
      in = w1; out = w1T;
      m0 = (r & 63) * 32; k0 = (r >> 6) * 32; K = 512; M = 2048;
    } else {
      int r = bid - 2048;
      in = w2; out = w2T;
      m0 = (r & 15) * 32; k0 = (r >> 4) * 32; K = 2048; M = 512;
    }
    for (int i = ty; i < 32; i += 8)
      tile[i][tx] = in[(size_t)(k0 + i) * M + m0 + tx];
    __syncthreads();
    for (int i = ty; i < 32; i += 8)
      out[(size_t)(m0 + i) * K + k0 + tx] = (bf16)tile[tx][i];
  } else if (bid < 5120) {
    int r = bid - 3072;
    int w0 = r * 128 + (tid >> 6) * 32;
    int lane = tid & 63;
#pragma unroll 4
    for (int i = 0; i < 32; ++i) {
      int w = w0 + i;
      int v = mpad[(size_t)w * 64 + lane];
      unsigned long long bmask = __ballot(v != 0);
      if (lane == 0) mbits[w] = bmask;
    }
  } else {
    int r = bid - 5120;
    size_t idx = ((size_t)r * 256 + tid) * 8;
    int sel = (int)(idx >> 22);
    size_t off = idx & ((1u << 22) - 1);
    const float* src = (sel == 0) ? qx : (sel == 1) ? kx : vx;
    float4 a = *(const float4*)(src + off);
    float4 b = *(const float4*)(src + off + 4);
    bf16x8 o;
    o[0] = (bf16)a.x; o[1] = (bf16)a.y; o[2] = (bf16)a.z; o[3] = (bf16)a.w;
    o[4] = (bf16)b.x; o[5] = (bf16)b.y; o[6] = (bf16)b.z; o[7] = (bf16)b.w;
    *(bf16x8*)(xb + idx) = o;
  }
}

// ---- epilogue helper ------------------------------------------------------
template <int EPI>
__device__ __forceinline__ void epi_store(void* Cout, int n, int m, int M,
                                          float val) {
  if constexpr (EPI == 3) {  // GELU -> bf16
    ((bf16*)Cout)[(size_t)n * M + m] = (bf16)gelu_f(val);
  } else if constexpr (EPI == 4) {  // f32
    ((float*)Cout)[(size_t)n * M + m] = val;
  } else {  // f32 accumulate
    ((float*)Cout)[(size_t)n * M + m] += val;
  }
}

// ---- GEMM: C[N][M] = A[N][K] @ Bt[M][K]^T + bias --------------------------
// v14: BK=32 double-buffer, ONE barrier per K-step, prefetch under compute.
// WIDE: 128x128 tile, wave = 64x64 quadrant, acc 4x4.
// TALL: 128x64 tile, wave = 32 rows x 64 cols, acc 2x4. grid.x = M/64.
// Per-buffer: 4 k-planes (plane p = k-chunk of 8); frag plane = quad.
template <int EPI, bool TALL>
__global__ void __launch_bounds__(256) gemm_bt(const bf16* __restrict__ A,
                                               const bf16* __restrict__ Bt,
                                               const float* __restrict__ bias,
                                               void* __restrict__ Cout,
                                               int M, int K, int lda, int ldb) {
  __shared__ __attribute__((aligned(16))) char As[2][4 * PLANE128];
  __shared__ __attribute__((aligned(16))) char Bs[2][TALL ? 4 * PLANE64
                                                         : 4 * PLANE128];
  int tid = threadIdx.x, wave = tid >> 6, lane = tid & 63;
  int lrow = lane & 15, quad = lane >> 4;
  int n0 = blockIdx.y * 128;
  int m0 = blockIdx.x * (TALL ? 64 : 128);
  int wr = wave >> 1, wc = wave & 1;  // WIDE quadrant
  floatx4 zero4 = {0.f, 0.f, 0.f, 0.f};
  constexpr int NI = TALL ? 2 : 4;
  floatx4 acc[NI][4];
#pragma unroll
  for (int i = 0; i < NI; ++i)
#pragma unroll
    for (int j = 0; j < 4; ++j) acc[i][j] = zero4;

  // wave covers k-plane p=wave of both A and B tiles (4 planes, 4 waves)
  auto stage = [&](int buf, int k0) {
    int p = wave;
#pragma unroll
    for (int j = 0; j < 2; ++j) {
      int row = j * 64 + lane;
      load_lds_16(A + (size_t)(n0 + row) * lda + k0 + p * 8,
                  As[buf] + p * PLANE128 + j * 1024 + lane * 16);
    }
    if constexpr (TALL) {
      load_lds_16(Bt + (size_t)(m0 + lane) * ldb + k0 + p * 8,
                  Bs[buf] + p * PLANE64 + lane * 16);
    } else {
#pragma unroll
      for (int j = 0; j < 2; ++j) {
        int row = j * 64 + lane;
        load_lds_16(Bt + (size_t)(m0 + row) * ldb + k0 + p * 8,
                    Bs[buf] + p * PLANE128 + j * 1024 + lane * 16);
      }
    }
  };

  stage(0, 0);
  int nk = K >> 5;
  for (int t = 0; t < nk; ++t) {
    int cur = t & 1;
    // drains: buf[cur] staged+visible; prior reads of buf[cur^1] retired.
    __syncthreads();
    if (t + 1 < nk) stage(cur ^ 1, (t + 1) * 32);  // hides under compute
    bf16x8 af[NI], bfr[4];
#pragma unroll
    for (int i = 0; i < NI; ++i) {
      int row = (TALL ? wave * 32 : wr * 64) + i * 16 + lrow;
      af[i] = *(const bf16x8*)(As[cur] + quad * PLANE128 + row * 16);
    }
#pragma unroll
    for (int j = 0; j < 4; ++j) {
      if constexpr (TALL)
        bfr[j] = *(const bf16x8*)(Bs[cur] + quad * PLANE64 +
                                  (j * 16 + lrow) * 16);
      else
        bfr[j] = *(const bf16x8*)(Bs[cur] + quad * PLANE128 +
                                  (wc * 64 + j * 16 + lrow) * 16);
    }
#pragma unroll
    for (int i = 0; i < NI; ++i)
#pragma unroll
      for (int j = 0; j < 4; ++j)
        acc[i][j] = mfma_bf16(af[i], bfr[j], acc[i][j]);
  }
  float bv[4];
#pragma unroll
  for (int j = 0; j < 4; ++j) {
    int m = m0 + (TALL ? 0 : wc * 64) + j * 16 + lrow;
    bv[j] = (EPI == 5) ? 0.f : bias[m];
  }
#pragma unroll
  for (int i = 0; i < NI; ++i)
#pragma unroll
    for (int j = 0; j < 4; ++j)
#pragma unroll
      for (int r = 0; r < 4; ++r) {
        int n = n0 + (TALL ? wave * 32 : wr * 64) + i * 16 + quad * 4 + r;
        int m = m0 + (TALL ? 0 : wc * 64) + j * 16 + lrow;
        epi_store<EPI>(Cout, n, m, M, acc[i][j][r] + bv[j]);
      }
}

// ---- fused QKV: one dispatch over cast-bf16 {qx,kx,vx} --------------------
// grid (4, 192): seg = y>>6. v14: BK=32 dbuf one-barrier schedule like gemm_bt.
// Q out (seg0): [B,H,L,DK] pre-scaled by 0.125*log2e.
// K out (seg1): tiled [BH][L/64][dchunk=8][row=64][8]  (plane = d-chunk)
// V out (seg2): tiled [BH][L/64][kchunk=8][d=64][8]    (plane = k-chunk)
__global__ void __launch_bounds__(256) qkv_k(const bf16* __restrict__ xb,
                                             const bf16* __restrict__ wqT,
                                             const bf16* __restrict__ wkT,
                                             const bf16* __restrict__ wvT,
                                             const float* __restrict__ bq,
                                             const float* __restrict__ bk,
                                             const float* __restrict__ bv_,
                                             bf16* __restrict__ qh,
                                             bf16* __restrict__ kh,
                                             bf16* __restrict__ vt) {
  __shared__ __attribute__((aligned(16))) char As[2][4 * PLANE128];
  __shared__ __attribute__((aligned(16))) char Bs[2][4 * PLANE128];
  int tid = threadIdx.x, wave = tid >> 6, lane = tid & 63;
  int lrow = lane & 15, quad = lane >> 4;
  int seg = blockIdx.y >> 6;
  int n0 = (blockIdx.y & 63) * 128, m0 = blockIdx.x * 128;
  const bf16* Af = xb + ((size_t)seg << 22);
  const bf16* Bt = (seg == 0) ? wqT : (seg == 1) ? wkT : wvT;
  const float* bias = (seg == 0) ? bq : (seg == 1) ? bk : bv_;
  bf16* out = (seg == 0) ? qh : (seg == 1) ? kh : vt;
  int wr = wave >> 1, wc = wave & 1;
  floatx4 zero4 = {0.f, 0.f, 0.f, 0.f};
  floatx4 acc[4][4];
#pragma unroll
  for (int i = 0; i < 4; ++i)
#pragma unroll
    for (int j = 0; j < 4; ++j) acc[i][j] = zero4;

  auto stage = [&](int buf, int k0) {
    int p = wave;
#pragma unroll
    for (int j = 0; j < 2; ++j) {
      int row = j * 64 + lane;
      load_lds_16(Af + (size_t)(n0 + row) * 512 + k0 + p * 8,
                  As[buf] + p * PLANE128 + j * 1024 + lane * 16);
      load_lds_16(Bt + (size_t)(m0 + row) * 512 + k0 + p * 8,
                  Bs[buf] + p * PLANE128 + j * 1024 + lane * 16);
    }
  };

  stage(0, 0);
  for (int t = 0; t < 16; ++t) {
    int cur = t & 1;
    __syncthreads();
    if (t < 15) stage(cur ^ 1, (t + 1) * 32);
    bf16x8 af[4], bfr[4];
#pragma unroll
    for (int i = 0; i < 4; ++i)
      af[i] = *(const bf16x8*)(As[cur] + quad * PLANE128 +
                               (wr * 64 + i * 16 + lrow) * 16);
#pragma unroll
    for (int j = 0; j < 4; ++j)
      bfr[j] = *(const bf16x8*)(Bs[cur] + quad * PLANE128 +
                                (wc * 64 + j * 16 + lrow) * 16);
#pragma unroll
    for (int i = 0; i < 4; ++i)
#pragma unroll
      for (int j = 0; j < 4; ++j) acc[i][j] = mfma_bf16(af[i], bfr[j], acc[i][j]);
  }
  float bvv[4];
#pragma unroll
  for (int j = 0; j < 4; ++j) bvv[j] = bias[m0 + wc * 64 + j * 16 + lrow];
  const float qscale = 0.1803368801f;  // 0.125 * log2(e), folded into Q
#pragma unroll
  for (int i = 0; i < 4; ++i)
#pragma unroll
    for (int j = 0; j < 4; ++j)
#pragma unroll
      for (int r = 0; r < 4; ++r) {
        int n = n0 + wr * 64 + i * 16 + quad * 4 + r;
        int m = m0 + wc * 64 + j * 16 + lrow;
        float val = acc[i][j][r] + bvv[j];
        int bb = n >> 11, l = n & 2047, hh = m >> 6, d = m & 63;
        if (seg == 0) {
          out[((size_t)((bb * 8 + hh) * 2048 + l)) * 64 + d] =
              (bf16)(val * qscale);
        } else {
          size_t tb_ = ((size_t)((bb * 8 + hh) * 32 + (l >> 6))) * 4096;
          if (seg == 1)
            out[tb_ + (d >> 3) * 512 + (l & 63) * 8 + (d & 7)] = (bf16)val;
          else
            out[tb_ + ((l >> 3) & 7) * 512 + d * 8 + (l & 7)] = (bf16)val;
        }
      }
}

// ---- flash attention (r11-proven): 8 waves, kv-split, tiled K/V staging ---
// waves 0-3 (hw=0): kt 0..15; waves 4-7 (hw=1): kt 16..31. Each half has its
// own dbuf K/V LDS stream; every global_load_lds reads contiguous 1KB from
// the tiled K/V layouts. QI=2, swapped QK^T, permlane P-redistribution,
// l via ones-MFMA, in-block (O,l) combine. Q pre-scaled in qkv_k.
__global__ void __launch_bounds__(512, 4) attn_k(const bf16* __restrict__ Qh,
                                                 const bf16* __restrict__ Kh,
                                                 const bf16* __restrict__ Vt,
                                                 const unsigned long long* __restrict__ MB,
                                                 bf16* __restrict__ Z) {
  __shared__ __attribute__((aligned(16))) char smem[8 * KVCH];
  int qt = blockIdx.x, h = blockIdx.y, b = blockIdx.z;
  int tid = threadIdx.x, wave = tid >> 6, lane = tid & 63;
  int hw = wave >> 2, wl = wave & 3;  // kv-half, local wave
  int lrow = lane & 15, quad = lane >> 4;
  int q0 = qt * 128;
  size_t headbase = (size_t)(b * 8 + h) * 2048 * 64;  // == (b*8+h)*32*4096

  bf16x8 qf[2][2];
#pragma unroll
  for (int u = 0; u < 2; ++u) {
    const bf16* Qp =
        Qh + headbase + (size_t)(q0 + wl * 32 + u * 16 + lrow) * 64 + quad * 8;
    qf[u][0] = *(const bf16x8*)Qp;
    qf[u][1] = *(const bf16x8*)(Qp + 32);
  }

  floatx4 zero4 = {0.f, 0.f, 0.f, 0.f};
  floatx4 o_acc[2][4], acc_l[2];
#pragma unroll
  for (int u = 0; u < 2; ++u) {
    acc_l[u] = zero4;
#pragma unroll
    for (int dt = 0; dt < 4; ++dt) o_acc[u][dt] = zero4;
  }
  bf16x8 ones;
#pragma unroll
  for (int j = 0; j < 8; ++j) ones[j] = (bf16)1.0f;

  const bf16* Kt0 = Kh + headbase;  // tiled: [32 tiles][4096]
  const bf16* Vt0 = Vt + headbase;
  // lane owns q-rows {q0+wl*32+lrow, +16}: one mask word per u per kt
  const uint2* MB0 =
      (const uint2*)(MB + ((size_t)b * 2048 + q0 + wl * 32 + lrow) * 32);
  int sh = quad * 4;  // bit offset within 16-bit mask segment

  char* KsH = smem + hw * 2 * KVCH;             // this half's K tiles [dbuf]
  char* VsH = smem + 4 * KVCH + hw * 2 * KVCH;  // this half's V tiles [dbuf]

  // stage tile kt into dbuf buf: 2 contiguous-1KB loads per wave per array
  auto stage = [&](int buf, int kt) {
    const bf16* Ktile = Kt0 + (size_t)kt * 4096;
    const bf16* Vtile = Vt0 + (size_t)kt * 4096;
#pragma unroll
    for (int j = 0; j < 2; ++j) {
      int p = wl * 2 + j;
      load_lds_16(Ktile + p * 512 + lane * 8,
                  KsH + buf * KVCH + p * PLANE64 + lane * 16);
      load_lds_16(Vtile + p * 512 + lane * 8,
                  VsH + buf * KVCH + p * PLANE64 + lane * 16);
    }
  };

  int ktbase = hw * 16;
  stage(0, ktbase);
  uint2 mwc[2] = {MB0[ktbase], MB0[512 + ktbase]};

  for (int it = 0; it < 16; ++it) {
    int kt = ktbase + it;
    int cur = it & 1;
    // drains: buf[cur] staging complete+visible; all waves' reads of
    // buf[cur^1] (from iter it-1) retired -> safe to overwrite it below.
    __syncthreads();
    uint2 mwn[2];
    if (it < 15) {
      stage(cur ^ 1, kt + 1);  // HBM/L2 latency hides under this it's compute
      mwn[0] = MB0[kt + 1];
      mwn[1] = MB0[512 + kt + 1];
    }
    const char* Kc = KsH + cur * KVCH;
    const char* Vc = VsH + cur * KVCH;
    unsigned S[2][4][2];  // [u][nt][pr] packed bf16x2 of masked exp scores
#pragma unroll
    for (int nt = 0; nt < 4; ++nt) {
      int R = nt * 16 + lrow;
      bf16x8 k0f = *(const bf16x8*)(Kc + quad * PLANE64 + R * 16);
      bf16x8 k1f = *(const bf16x8*)(Kc + (quad + 4) * PLANE64 + R * 16);
#pragma unroll
      for (int u = 0; u < 2; ++u) {
        floatx4 aa = zero4;
        aa = mfma_bf16(k0f, qf[u][0], aa);  // swapped: D[k_local][q] = S^T
        aa = mfma_bf16(k1f, qf[u][1], aa);
        unsigned wn = ((nt & 2) ? mwc[u].y : mwc[u].x) >> ((nt & 1) * 16 + sh);
        float e[4];
#pragma unroll
        for (int r = 0; r < 4; ++r)
          e[r] = (wn & (1u << r)) ? __builtin_amdgcn_exp2f(aa[r]) : 0.f;
        S[u][nt][0] = pack2(e[0], e[1]);
        S[u][nt][1] = pack2(e[2], e[3]);
      }
    }
    // V-frags read once, shared by both q-halves
    bf16x8 v0[4], v1[4];
#pragma unroll
    for (int dt = 0; dt < 4; ++dt) {
      int R = dt * 16 + lrow;
      v0[dt] = *(const bf16x8*)(Vc + quad * PLANE64 + R * 16);
      v1[dt] = *(const bf16x8*)(Vc + (quad + 4) * PLANE64 + R * 16);
    }
#pragma unroll
    for (int u = 0; u < 2; ++u) {
      // in-register redistribution: S[u][nt][pr] -> pf0/pf1 PV A-frags
      union { unsigned w[4]; bf16x8 v; } pf[2];
#pragma unroll
      for (int half = 0; half < 2; ++half)
#pragma unroll
        for (int pr = 0; pr < 2; ++pr) {
          uint2v a = __builtin_amdgcn_permlane32_swap(
              S[u][half * 2][pr], S[u][half * 2 + 1][pr], false, false);
          uint2v c = __builtin_amdgcn_permlane16_swap(a[0], a[1], false, false);
          pf[half].w[pr] = c[0];      // word pr   (k-offset 2*pr within 8)
          pf[half].w[pr + 2] = c[1];  // word pr+2 (k-offset 4+2*pr)
        }
      bf16x8 pf0 = pf[0].v, pf1 = pf[1].v;
      __builtin_amdgcn_s_setprio(1);
      acc_l[u] = mfma_bf16(pf0, ones, acc_l[u]);  // row sums -> l
      acc_l[u] = mfma_bf16(pf1, ones, acc_l[u]);
#pragma unroll
      for (int dt = 0; dt < 4; ++dt) {
        o_acc[u][dt] = mfma_bf16(pf0, v0[dt], o_acc[u][dt]);
        o_acc[u][dt] = mfma_bf16(pf1, v1[dt], o_acc[u][dt]);
      }
      __builtin_amdgcn_s_setprio(0);
    }
    if (it < 15) { mwc[0] = mwn[0]; mwc[1] = mwn[1]; }
  }

  // ---- in-block combine: half1 dumps partials to LDS, half0 merges --------
  __syncthreads();  // all staging/frag LDS traffic done; smem reusable
  float* cb = (float*)smem;  // 256 lanes * 40 f32 = 40 KB
  int cbase = (wl * 64 + lane) * 40;
  if (hw == 1) {
#pragma unroll
    for (int u = 0; u < 2; ++u) {
#pragma unroll
      for (int dt = 0; dt < 4; ++dt)
        *(floatx4*)(cb + cbase + (u * 4 + dt) * 4) = o_acc[u][dt];
      *(floatx4*)(cb + cbase + 32 + u * 4) = acc_l[u];
    }
  }
  __syncthreads();
  if (hw == 0) {
#pragma unroll
    for (int u = 0; u < 2; ++u) {
#pragma unroll
      for (int dt = 0; dt < 4; ++dt)
        o_acc[u][dt] += *(const floatx4*)(cb + cbase + (u * 4 + dt) * 4);
      acc_l[u] += *(const floatx4*)(cb + cbase + 32 + u * 4);
    }
#pragma unroll
    for (int u = 0; u < 2; ++u) {
      float lr[4];
#pragma unroll
      for (int r = 0; r < 4; ++r) lr[r] = 1.0f / acc_l[u][r];
#pragma unroll
      for (int dt = 0; dt < 4; ++dt)
#pragma unroll
        for (int r = 0; r < 4; ++r) {
          int qrow = q0 + wl * 32 + u * 16 + quad * 4 + r;
          int d = dt * 16 + lrow;
          Z[((size_t)(b * 2048 + qrow)) * 512 + h * 64 + d] =
              (bf16)(o_acc[u][dt][r] * lr[r]);
        }
    }
  }
}

// ---- layernorm: out = LN(a + s_f32) * g + b -------------------------------
template <bool A_BF16, bool OUT_BF16>
__global__ void __launch_bounds__(256) ln_k(const void* __restrict__ a_,
                                            const float* __restrict__ s,
                                            const float* __restrict__ g,
                                            const float* __restrict__ bta,
                                            void* __restrict__ out_) {
  int row = blockIdx.x * 4 + (threadIdx.x >> 6);
  int lane = threadIdx.x & 63;
  size_t base = (size_t)row * 512 + lane * 8;
  float x[8];
  float4 sa = *(const float4*)(s + base);
  float4 sb = *(const float4*)(s + base + 4);
  if constexpr (A_BF16) {
    bf16x8 av = *(const bf16x8*)((const bf16*)a_ + base);
    x[0] = (float)av[0] + sa.x; x[1] = (float)av[1] + sa.y;
    x[2] = (float)av[2] + sa.z; x[3] = (float)av[3] + sa.w;
    x[4] = (float)av[4] + sb.x; x[5] = (float)av[5] + sb.y;
    x[6] = (float)av[6] + sb.z; x[7] = (float)av[7] + sb.w;
  } else {
    float4 a0 = *(const float4*)((const float*)a_ + base);
    float4 a1 = *(const float4*)((const float*)a_ + base + 4);
    x[0] = a0.x + sa.x; x[1] = a0.y + sa.y; x[2] = a0.z + sa.z; x[3] = a0.w + sa.w;
    x[4] = a1.x + sb.x; x[5] = a1.y + sb.y; x[6] = a1.z + sb.z; x[7] = a1.w + sb.w;
  }
  float sum = 0.f;
#pragma unroll
  for (int i = 0; i < 8; ++i) sum += x[i];
#pragma unroll
  for (int off = 1; off < 64; off <<= 1) sum += __shfl_xor(sum, off, 64);
  float mu = sum * (1.0f / 512.0f);
  float vs = 0.f;
#pragma unroll
  for (int i = 0; i < 8; ++i) { float d = x[i] - mu; vs += d * d; }
#pragma unroll
  for (int off = 1; off < 64; off <<= 1) vs += __shfl_xor(vs, off, 64);
  float rstd = rsqrtf(vs * (1.0f / 512.0f) + 1e-5f);
  float4 g0 = *(const float4*)(g + lane * 8);
  float4 g1 = *(const float4*)(g + lane * 8 + 4);
  float4 b0 = *(const float4*)(bta + lane * 8);
  float4 b1 = *(const float4*)(bta + lane * 8 + 4);
  float gg[8] = {g0.x, g0.y, g0.z, g0.w, g1.x, g1.y, g1.z, g1.w};
  float bb[8] = {b0.x, b0.y, b0.z, b0.w, b1.x, b1.y, b1.z, b1.w};
  if constexpr (OUT_BF16) {
    bf16x8 o;
#pragma unroll
    for (int i = 0; i < 8; ++i)
      o[i] = (bf16)((x[i] - mu) * rstd * gg[i] + bb[i]);
    *(bf16x8*)((bf16*)out_ + base) = o;
  } else {
    float4 o0, o1;
    o0.x = (x[0] - mu) * rstd * gg[0] + bb[0];
    o0.y = (x[1] - mu) * rstd * gg[1] + bb[1];
    o0.z = (x[2] - mu) * rstd * gg[2] + bb[2];
    o0.w = (x[3] - mu) * rstd * gg[3] + bb[3];
    o1.x = (x[4] - mu) * rstd * gg[4] + bb[4];
    o1.y = (x[5] - mu) * rstd * gg[5] + bb[5];
    o1.z = (x[6] - mu) * rstd * gg[6] + bb[6];
    o1.w = (x[7] - mu) * rstd * gg[7] + bb[7];
    *(float4*)((float*)out_ + base) = o0;
    *(float4*)((float*)out_ + base + 4) = o1;
  }
}

extern "C" void kernel_launch(void* const* d_in, const int* in_sizes, int n_in,
                              void* d_out, int out_size, void* d_ws, size_t ws_size,
                              hipStream_t stream) {
  const float* qx = (const float*)d_in[0];
  const float* kx = (const float*)d_in[1];
  const float* vx = (const float*)d_in[2];
  const int* maskPAD = (const int*)d_in[3];
  const float* wq = (const float*)d_in[4];
  const float* bq = (const float*)d_in[5];
  const float* wk = (const float*)d_in[6];
  const float* bk = (const float*)d_in[7];
  const float* wv = (const float*)d_in[8];
  const float* bv = (const float*)d_in[9];
  const float* wo = (const float*)d_in[10];
  const float* bo = (const float*)d_in[11];
  const float* w1 = (const float*)d_in[12];
  const float* b1 = (const float*)d_in[13];
  const float* w2 = (const float*)d_in[14];
  const float* b2 = (const float*)d_in[15];
  const float* g1 = (const float*)d_in[16];
  const float* be1 = (const float*)d_in[17];
  const float* g2 = (const float*)d_in[18];
  const float* be2 = (const float*)d_in[19];

  char* w = (char*)d_ws;
  size_t off = 0;
  auto alloc = [&](size_t bytes) {
    void* p = w + off;
    off += (bytes + 255) & ~(size_t)255;
    return p;
  };
  bf16* wqT = (bf16*)alloc(512 * 512 * 2);
  bf16* wkT = (bf16*)alloc(512 * 512 * 2);
  bf16* wvT = (bf16*)alloc(512 * 512 * 2);
  bf16* woT = (bf16*)alloc(512 * 512 * 2);
  bf16* w1T = (bf16*)alloc(2048 * 512 * 2);
  bf16* w2T = (bf16*)alloc(512 * 2048 * 2);
  unsigned long long* mbits = (unsigned long long*)alloc((size_t)4 * 2048 * 32 * 8);
  bf16* xb = (bf16*)alloc((size_t)3 * 4194304 * 2);  // cast qx,kx,vx
  bf16* qh = (bf16*)alloc((size_t)8192 * 512 * 2);
  bf16* kh = (bf16*)alloc((size_t)8192 * 512 * 2);
  bf16* vt = (bf16*)alloc((size_t)8192 * 512 * 2);
  bf16* z = (bf16*)alloc((size_t)8192 * 512 * 2);
  float* s12 = (float*)qh;  // over qh+kh (dead after attn)
  bf16* zn = vt;            // vt dead after attn
  size_t h1_bytes = (size_t)8192 * 2048 * 2;
  bool big = (off + h1_bytes) <= ws_size;
  bf16* h1 = big ? (bf16*)alloc(h1_bytes) : z;

  // merged preprocessing: transposes + maskbits + cast3, one dispatch
  prep_k<<<11264, 256, 0, stream>>>(wq, wk, wv, wo, wqT, wkT, wvT, woT, w1, w1T,
                                    w2, w2T, maskPAD, mbits, qx, kx, vx, xb);
  // fused QKV (768 blocks), bf16 A via global_load_lds, dbuf BK=32
  qkv_k<<<dim3(4, 192), 256, 0, stream>>>(xb, wqT, wkT, wvT, bq, bk, bv,
                                          qh, kh, vt);
  // flash attention -> z (128 q-rows/block, 8 waves, kv-split, tiled K/V)
  attn_k<<<dim3(16, 8, 4), 512, 0, stream>>>(qh, kh, vt, mbits, z);
  // out projection (TALL, 512 blocks) + LN1
  gemm_bt<4, true><<<dim3(8, 64), 256, 0, stream>>>(z, woT, bo, s12, 512, 512,
                                                    512, 512);
  ln_k<false, true><<<2048, 256, 0, stream>>>(vx, s12, g1, be1, zn);
  if (big) {
    gemm_bt<3, false><<<dim3(16, 64), 256, 0, stream>>>(zn, w1T, b1, h1, 2048,
                                                        512, 512, 512);
    gemm_bt<4, true><<<dim3(8, 64), 256, 0, stream>>>(h1, w2T, b2, s12, 512,
                                                      2048, 2048, 2048);
  } else {
    for (int p = 0; p < 4; ++p) {
      gemm_bt<3, true><<<dim3(8, 64), 256, 0, stream>>>(
          zn, w1T + (size_t)p * 512 * 512, b1 + p * 512, h1, 512, 512, 512, 512);
      if (p == 0)
        gemm_bt<4, true><<<dim3(8, 64), 256, 0, stream>>>(
            h1, w2T + p * 512, b2, s12, 512, 512, 512, 2048);
      else
        gemm_bt<5, true><<<dim3(8, 64), 256, 0, stream>>>(
            h1, w2T + p * 512, nullptr, s12, 512, 512, 512, 2048);
    }
  }
  ln_k<true, false><<<2048, 256, 0, stream>>>(zn, s12, g2, be2, (float*)d_out);
}

// Round 11
// 381.828 us; speedup vs baseline: 1.2476x; 1.0559x over previous
//
#include <hip/hip_runtime.h>
#include <cstdint>

// Transformer Post-LN block, MI355X gfx950.
// B=4, L=2048, FEA=512, H=8, DK=64, FFN=2048. f32 I/O, bf16 MFMA, f32 accum.
// Round 15: ALL gemm operands moved to tiled [row/64][col/8][64][8] bf16
// layouts (1KB contiguous per staging gll, 8x fewer L2 requests — the r11
// attn fix applied to qkv/out-proj/FFN1/FFN2 A and B operands). Producers
// remapped: prep transposes (weights), cast3 (xb), attn Z, ln1 zn, FFN1 GELU
// h1. LDS contents byte-identical; compute untouched. gemm_bt gains kbase
// for fallback w2T k-slicing. attn unchanged from r13/14 (62.6 us).

typedef __bf16 bf16;
typedef __bf16 bf16x8 __attribute__((ext_vector_type(8)));
typedef __bf16 bf16x2 __attribute__((ext_vector_type(2)));
typedef float floatx4 __attribute__((ext_vector_type(4)));
typedef unsigned uint2v __attribute__((ext_vector_type(2)));

__device__ __forceinline__ floatx4 mfma_bf16(bf16x8 a, bf16x8 b, floatx4 c) {
  return __builtin_amdgcn_mfma_f32_16x16x32_bf16(a, b, c, 0, 0, 0);
}

// async global->LDS, 16B/lane; LDS dest = wave-uniform base + lane*16.
__device__ __forceinline__ void load_lds_16(const void* g, void* l) {
  auto gp = reinterpret_cast<const void __attribute__((address_space(1)))*>(
      reinterpret_cast<uintptr_t>(g));
  auto lp = reinterpret_cast<void __attribute__((address_space(3)))*>(
      (unsigned int)reinterpret_cast<uintptr_t>(l));
  __builtin_amdgcn_global_load_lds(gp, lp, 16, 0, 0);
}

// tiled [row/64][col/8][64][8] element index for a [N][C] bf16 matrix
__device__ __forceinline__ size_t tix(int row, int col, int C) {
  return ((size_t)((row >> 6) * (C >> 3) + (col >> 3)) << 9) +
         ((row & 63) << 3) + (col & 7);
}

// pack two f32 -> u32 of 2 bf16 (compiler emits v_cvt_pk_bf16_f32)
__device__ __forceinline__ unsigned pack2(float a, float b) {
  bf16x2 p;
  p[0] = (bf16)a;
  p[1] = (bf16)b;
  return __builtin_bit_cast(unsigned, p);
}

// tanh-form GELU (max |err| ~1e-3, well under 0.0988 threshold)
__device__ __forceinline__ float gelu_f(float x) {
  float t = 0.7978845608f * (x + 0.044715f * x * x * x);
  float e = __builtin_amdgcn_exp2f(t * 2.885390082f);  // e^(2t)
  float th = 1.0f - 2.0f * __builtin_amdgcn_rcpf(e + 1.0f);
  return 0.5f * x * (1.0f + th);
}

// k-plane LDS geometry: plane = rows*16B, +16B pad between planes.
#define PLANE128 2064  // 128 rows * 16B + 16B pad
#define PLANE64 1040   // 64 rows * 16B + 16B pad
#define KVCH 8320      // 8 planes * PLANE64 (one K or V tile)

// ---- merged preprocessing: one dispatch, 11264 blocks ---------------------
// [0,1024):    transpose4 (wq,wk,wv,wo -> bf16 T, tiled)
// [1024,2048): transpose w1 (K=512,M=2048, tiled)
// [2048,3072): transpose w2 (K=2048,M=512, tiled)
// [3072,5120): maskbits (2048 blocks)
// [5120,11264): cast3 qx,kx,vx -> bf16 tiled (6144 blocks)
__global__ void __launch_bounds__(256) prep_k(
    const float* __restrict__ wq, const float* __restrict__ wk,
    const float* __restrict__ wv, const float* __restrict__ wo,
    bf16* __restrict__ wqT, bf16* __restrict__ wkT, bf16* __restrict__ wvT,
    bf16* __restrict__ woT, const float* __restrict__ w1,
    bf16* __restrict__ w1T, const float* __restrict__ w2,
    bf16* __restrict__ w2T, const int* __restrict__ mpad,
    unsigned long long* __restrict__ mbits, const float* __restrict__ qx,
    const float* __restrict__ kx, const float* __restrict__ vx,
    bf16* __restrict__ xb) {
  __shared__ float tile[32][33];
  int bid = blockIdx.x, tid = threadIdx.x;
  int tx = tid & 31, ty = tid >> 5;
  if (bid < 3072) {
    const float* in;
    bf16* out;
    int m0, k0, K, M;
    if (bid < 1024) {
      int z = bid >> 8, r = bid & 255;
      in = (z == 0) ? wq : (z == 1) ? wk : (z == 2) ? wv : wo;
      out = (z == 0) ? wqT : (z == 1) ? wkT : (z == 2) ? wvT : woT;
      m0 = (r & 15) * 32; k0 = (r >> 4) * 32; K = 512; M = 512;
    } else if (bid < 2048) {
      int r = bid - 1024;
      in = w1; out = w1T;
      m0 = (r & 63) * 32; k0 = (r >> 6) * 32; K = 512; M = 2048;
    } else {
      int r = bid - 2048;
      in = w2; out = w2T;
      m0 = (r & 15) * 32; k0 = (r >> 4) * 32; K = 2048; M = 512;
    }
    for (int i = ty; i < 32; i += 8)
      tile[i][tx] = in[(size_t)(k0 + i) * M + m0 + tx];
    __syncthreads();
    for (int i = ty; i < 32; i += 8)
      out[tix(m0 + i, k0 + tx, K)] = (bf16)tile[tx][i];
  } else if (bid < 5120) {
    int r = bid - 3072;
    int w0 = r * 128 + (tid >> 6) * 32;
    int lane = tid & 63;
#pragma unroll 4
    for (int i = 0; i < 32; ++i) {
      int w = w0 + i;
      int v = mpad[(size_t)w * 64 + lane];
      unsigned long long bmask = __ballot(v != 0);
      if (lane == 0) mbits[w] = bmask;
    }
  } else {
    int r = bid - 5120;
    size_t idx = ((size_t)r * 256 + tid) * 8;
    int sel = (int)(idx >> 22);
    size_t off = idx & ((1u << 22) - 1);
    const float* src = (sel == 0) ? qx : (sel == 1) ? kx : vx;
    float4 a = *(const float4*)(src + off);
    float4 b = *(const float4*)(src + off + 4);
    bf16x8 o;
    o[0] = (bf16)a.x; o[1] = (bf16)a.y; o[2] = (bf16)a.z; o[3] = (bf16)a.w;
    o[4] = (bf16)b.x; o[5] = (bf16)b.y; o[6] = (bf16)b.z; o[7] = (bf16)b.w;
    int row = (int)(off >> 9), k = (int)(off & 511);
    *(bf16x8*)(xb + ((size_t)sel << 22) + tix(row, k, 512)) = o;
  }
}

// ---- epilogue helper ------------------------------------------------------
template <int EPI>
__device__ __forceinline__ void epi_store(void* Cout, int n, int m, int M,
                                          float val) {
  if constexpr (EPI == 3) {  // GELU -> bf16, TILED output
    ((bf16*)Cout)[tix(n, m, M)] = (bf16)gelu_f(val);
  } else if constexpr (EPI == 4) {  // f32 linear
    ((float*)Cout)[(size_t)n * M + m] = val;
  } else {  // f32 accumulate
    ((float*)Cout)[(size_t)n * M + m] += val;
  }
}

// ---- GEMM: C[N][M] = A[N][K] @ Bt[M][K]^T + bias --------------------------
// BK=32 double-buffer, one barrier per K-step, prefetch under compute.
// A and Bt are TILED [row/64][k/8][64][8]; each staging gll reads 1KB chunk.
// WIDE: 128x128 tile, wave = 64x64 quadrant, acc 4x4.
// TALL: 128x64 tile, wave = 32 rows x 64 cols, acc 2x4. grid.x = M/64.
// kbase: k-origin offset into Bt's tiled k-chunks (fallback slicing).
template <int EPI, bool TALL>
__global__ void __launch_bounds__(256) gemm_bt(const bf16* __restrict__ A,
                                               const bf16* __restrict__ Bt,
                                               const float* __restrict__ bias,
                                               void* __restrict__ Cout,
                                               int M, int K, int lda, int ldb,
                                               int kbase) {
  __shared__ __attribute__((aligned(16))) char As[2][4 * PLANE128];
  __shared__ __attribute__((aligned(16))) char Bs[2][TALL ? 4 * PLANE64
                                                         : 4 * PLANE128];
  int tid = threadIdx.x, wave = tid >> 6, lane = tid & 63;
  int lrow = lane & 15, quad = lane >> 4;
  int n0 = blockIdx.y * 128;
  int m0 = blockIdx.x * (TALL ? 64 : 128);
  int wr = wave >> 1, wc = wave & 1;  // WIDE quadrant
  floatx4 zero4 = {0.f, 0.f, 0.f, 0.f};
  constexpr int NI = TALL ? 2 : 4;
  floatx4 acc[NI][4];
#pragma unroll
  for (int i = 0; i < NI; ++i)
#pragma unroll
    for (int j = 0; j < 4; ++j) acc[i][j] = zero4;

  int ca = lda >> 3, cb = ldb >> 3;
  // wave covers k-plane p=wave (k-chunk) of both A and B tiles
  auto stage = [&](int buf, int k0) {
    int p = wave;
    int kc = (k0 >> 3) + p;
    int kcb = ((kbase + k0) >> 3) + p;
#pragma unroll
    for (int j = 0; j < 2; ++j) {
      load_lds_16(A + ((size_t)(((n0 >> 6) + j) * ca + kc) << 9) + lane * 8,
                  As[buf] + p * PLANE128 + j * 1024 + lane * 16);
    }
    if constexpr (TALL) {
      load_lds_16(Bt + ((size_t)((m0 >> 6) * cb + kcb) << 9) + lane * 8,
                  Bs[buf] + p * PLANE64 + lane * 16);
    } else {
#pragma unroll
      for (int j = 0; j < 2; ++j) {
        load_lds_16(Bt + ((size_t)(((m0 >> 6) + j) * cb + kcb) << 9) + lane * 8,
                    Bs[buf] + p * PLANE128 + j * 1024 + lane * 16);
      }
    }
  };

  stage(0, 0);
  int nk = K >> 5;
  for (int t = 0; t < nk; ++t) {
    int cur = t & 1;
    // drains: buf[cur] staged+visible; prior reads of buf[cur^1] retired.
    __syncthreads();
    if (t + 1 < nk) stage(cur ^ 1, (t + 1) * 32);  // hides under compute
    bf16x8 af[NI], bfr[4];
#pragma unroll
    for (int i = 0; i < NI; ++i) {
      int row = (TALL ? wave * 32 : wr * 64) + i * 16 + lrow;
      af[i] = *(const bf16x8*)(As[cur] + quad * PLANE128 + row * 16);
    }
#pragma unroll
    for (int j = 0; j < 4; ++j) {
      if constexpr (TALL)
        bfr[j] = *(const bf16x8*)(Bs[cur] + quad * PLANE64 +
                                  (j * 16 + lrow) * 16);
      else
        bfr[j] = *(const bf16x8*)(Bs[cur] + quad * PLANE128 +
                                  (wc * 64 + j * 16 + lrow) * 16);
    }
#pragma unroll
    for (int i = 0; i < NI; ++i)
#pragma unroll
      for (int j = 0; j < 4; ++j)
        acc[i][j] = mfma_bf16(af[i], bfr[j], acc[i][j]);
  }
  float bv[4];
#pragma unroll
  for (int j = 0; j < 4; ++j) {
    int m = m0 + (TALL ? 0 : wc * 64) + j * 16 + lrow;
    bv[j] = (EPI == 5) ? 0.f : bias[m];
  }
#pragma unroll
  for (int i = 0; i < NI; ++i)
#pragma unroll
    for (int j = 0; j < 4; ++j)
#pragma unroll
      for (int r = 0; r < 4; ++r) {
        int n = n0 + (TALL ? wave * 32 : wr * 64) + i * 16 + quad * 4 + r;
        int m = m0 + (TALL ? 0 : wc * 64) + j * 16 + lrow;
        epi_store<EPI>(Cout, n, m, M, acc[i][j][r] + bv[j]);
      }
}

// ---- fused QKV: one dispatch over cast-bf16 {qx,kx,vx} --------------------
// grid (4, 192): seg = y>>6. BK=32 dbuf; A (xb) and B (w*T) TILED.
// Q out (seg0): [B,H,L,DK] pre-scaled by 0.125*log2e.
// K out (seg1): attn-tiled [BH][L/64][dchunk=8][row=64][8]
// V out (seg2): attn-tiled [BH][L/64][kchunk=8][d=64][8]
__global__ void __launch_bounds__(256) qkv_k(const bf16* __restrict__ xb,
                                             const bf16* __restrict__ wqT,
                                             const bf16* __restrict__ wkT,
                                             const bf16* __restrict__ wvT,
                                             const float* __restrict__ bq,
                                             const float* __restrict__ bk,
                                             const float* __restrict__ bv_,
                                             bf16* __restrict__ qh,
                                             bf16* __restrict__ kh,
                                             bf16* __restrict__ vt) {
  __shared__ __attribute__((aligned(16))) char As[2][4 * PLANE128];
  __shared__ __attribute__((aligned(16))) char Bs[2][4 * PLANE128];
  int tid = threadIdx.x, wave = tid >> 6, lane = tid & 63;
  int lrow = lane & 15, quad = lane >> 4;
  int seg = blockIdx.y >> 6;
  int n0 = (blockIdx.y & 63) * 128, m0 = blockIdx.x * 128;
  const bf16* Af = xb + ((size_t)seg << 22);
  const bf16* Bt = (seg == 0) ? wqT : (seg == 1) ? wkT : wvT;
  const float* bias = (seg == 0) ? bq : (seg == 1) ? bk : bv_;
  bf16* out = (seg == 0) ? qh : (seg == 1) ? kh : vt;
  int wr = wave >> 1, wc = wave & 1;
  floatx4 zero4 = {0.f, 0.f, 0.f, 0.f};
  floatx4 acc[4][4];
#pragma unroll
  for (int i = 0; i < 4; ++i)
#pragma unroll
    for (int j = 0; j < 4; ++j) acc[i][j] = zero4;

  auto stage = [&](int buf, int k0) {
    int p = wave;
    int kc = (k0 >> 3) + p;  // chunks-per-rowtile = 64 (K=512)
#pragma unroll
    for (int j = 0; j < 2; ++j) {
      load_lds_16(Af + ((size_t)(((n0 >> 6) + j) * 64 + kc) << 9) + lane * 8,
                  As[buf] + p * PLANE128 + j * 1024 + lane * 16);
      load_lds_16(Bt + ((size_t)(((m0 >> 6) + j) * 64 + kc) << 9) + lane * 8,
                  Bs[buf] + p * PLANE128 + j * 1024 + lane * 16);
    }
  };

  stage(0, 0);
  for (int t = 0; t < 16; ++t) {
    int cur = t & 1;
    __syncthreads();
    if (t < 15) stage(cur ^ 1, (t + 1) * 32);
    bf16x8 af[4], bfr[4];
#pragma unroll
    for (int i = 0; i < 4; ++i)
      af[i] = *(const bf16x8*)(As[cur] + quad * PLANE128 +
                               (wr * 64 + i * 16 + lrow) * 16);
#pragma unroll
    for (int j = 0; j < 4; ++j)
      bfr[j] = *(const bf16x8*)(Bs[cur] + quad * PLANE128 +
                                (wc * 64 + j * 16 + lrow) * 16);
#pragma unroll
    for (int i = 0; i < 4; ++i)
#pragma unroll
      for (int j = 0; j < 4; ++j) acc[i][j] = mfma_bf16(af[i], bfr[j], acc[i][j]);
  }
  float bvv[4];
#pragma unroll
  for (int j = 0; j < 4; ++j) bvv[j] = bias[m0 + wc * 64 + j * 16 + lrow];
  const float qscale = 0.1803368801f;  // 0.125 * log2(e), folded into Q
#pragma unroll
  for (int i = 0; i < 4; ++i)
#pragma unroll
    for (int j = 0; j < 4; ++j)
#pragma unroll
      for (int r = 0; r < 4; ++r) {
        int n = n0 + wr * 64 + i * 16 + quad * 4 + r;
        int m = m0 + wc * 64 + j * 16 + lrow;
        float val = acc[i][j][r] + bvv[j];
        int bb = n >> 11, l = n & 2047, hh = m >> 6, d = m & 63;
        if (seg == 0) {
          out[((size_t)((bb * 8 + hh) * 2048 + l)) * 64 + d] =
              (bf16)(val * qscale);
        } else {
          size_t tb_ = ((size_t)((bb * 8 + hh) * 32 + (l >> 6))) * 4096;
          if (seg == 1)
            out[tb_ + (d >> 3) * 512 + (l & 63) * 8 + (d & 7)] = (bf16)val;
          else
            out[tb_ + ((l >> 3) & 7) * 512 + d * 8 + (l & 7)] = (bf16)val;
        }
      }
}

// ---- flash attention (r11-proven): 8 waves, kv-split, tiled K/V staging ---
// Z output now TILED [row/64][col/8][64][8] for out-proj A staging.
__global__ void __launch_bounds__(512, 4) attn_k(const bf16* __restrict__ Qh,
                                                 const bf16* __restrict__ Kh,
                                                 const bf16* __restrict__ Vt,
                                                 const unsigned long long* __restrict__ MB,
                                                 bf16* __restrict__ Z) {
  __shared__ __attribute__((aligned(16))) char smem[8 * KVCH];
  int qt = blockIdx.x, h = blockIdx.y, b = blockIdx.z;
  int tid = threadIdx.x, wave = tid >> 6, lane = tid & 63;
  int hw = wave >> 2, wl = wave & 3;  // kv-half, local wave
  int lrow = lane & 15, quad = lane >> 4;
  int q0 = qt * 128;
  size_t headbase = (size_t)(b * 8 + h) * 2048 * 64;  // == (b*8+h)*32*4096

  bf16x8 qf[2][2];
#pragma unroll
  for (int u = 0; u < 2; ++u) {
    const bf16* Qp =
        Qh + headbase + (size_t)(q0 + wl * 32 + u * 16 + lrow) * 64 + quad * 8;
    qf[u][0] = *(const bf16x8*)Qp;
    qf[u][1] = *(const bf16x8*)(Qp + 32);
  }

  floatx4 zero4 = {0.f, 0.f, 0.f, 0.f};
  floatx4 o_acc[2][4], acc_l[2];
#pragma unroll
  for (int u = 0; u < 2; ++u) {
    acc_l[u] = zero4;
#pragma unroll
    for (int dt = 0; dt < 4; ++dt) o_acc[u][dt] = zero4;
  }
  bf16x8 ones;
#pragma unroll
  for (int j = 0; j < 8; ++j) ones[j] = (bf16)1.0f;

  const bf16* Kt0 = Kh + headbase;  // tiled: [32 tiles][4096]
  const bf16* Vt0 = Vt + headbase;
  // lane owns q-rows {q0+wl*32+lrow, +16}: one mask word per u per kt
  const uint2* MB0 =
      (const uint2*)(MB + ((size_t)b * 2048 + q0 + wl * 32 + lrow) * 32);
  int sh = quad * 4;  // bit offset within 16-bit mask segment

  char* KsH = smem + hw * 2 * KVCH;             // this half's K tiles [dbuf]
  char* VsH = smem + 4 * KVCH + hw * 2 * KVCH;  // this half's V tiles [dbuf]

  // stage tile kt into dbuf buf: 2 contiguous-1KB loads per wave per array
  auto stage = [&](int buf, int kt) {
    const bf16* Ktile = Kt0 + (size_t)kt * 4096;
    const bf16* Vtile = Vt0 + (size_t)kt * 4096;
#pragma unroll
    for (int j = 0; j < 2; ++j) {
      int p = wl * 2 + j;
      load_lds_16(Ktile + p * 512 + lane * 8,
                  KsH + buf * KVCH + p * PLANE64 + lane * 16);
      load_lds_16(Vtile + p * 512 + lane * 8,
                  VsH + buf * KVCH + p * PLANE64 + lane * 16);
    }
  };

  int ktbase = hw * 16;
  stage(0, ktbase);
  uint2 mwc[2] = {MB0[ktbase], MB0[512 + ktbase]};

  for (int it = 0; it < 16; ++it) {
    int kt = ktbase + it;
    int cur = it & 1;
    // drains: buf[cur] staging complete+visible; all waves' reads of
    // buf[cur^1] (from iter it-1) retired -> safe to overwrite it below.
    __syncthreads();
    uint2 mwn[2];
    if (it < 15) {
      stage(cur ^ 1, kt + 1);  // HBM/L2 latency hides under this it's compute
      mwn[0] = MB0[kt + 1];
      mwn[1] = MB0[512 + kt + 1];
    }
    const char* Kc = KsH + cur * KVCH;
    const char* Vc = VsH + cur * KVCH;
    unsigned S[2][4][2];  // [u][nt][pr] packed bf16x2 of masked exp scores
#pragma unroll
    for (int nt = 0; nt < 4; ++nt) {
      int R = nt * 16 + lrow;
      bf16x8 k0f = *(const bf16x8*)(Kc + quad * PLANE64 + R * 16);
      bf16x8 k1f = *(const bf16x8*)(Kc + (quad + 4) * PLANE64 + R * 16);
#pragma unroll
      for (int u = 0; u < 2; ++u) {
        floatx4 aa = zero4;
        aa = mfma_bf16(k0f, qf[u][0], aa);  // swapped: D[k_local][q] = S^T
        aa = mfma_bf16(k1f, qf[u][1], aa);
        unsigned wn = ((nt & 2) ? mwc[u].y : mwc[u].x) >> ((nt & 1) * 16 + sh);
        float e[4];
#pragma unroll
        for (int r = 0; r < 4; ++r)
          e[r] = (wn & (1u << r)) ? __builtin_amdgcn_exp2f(aa[r]) : 0.f;
        S[u][nt][0] = pack2(e[0], e[1]);
        S[u][nt][1] = pack2(e[2], e[3]);
      }
    }
    // V-frags read once, shared by both q-halves
    bf16x8 v0[4], v1[4];
#pragma unroll
    for (int dt = 0; dt < 4; ++dt) {
      int R = dt * 16 + lrow;
      v0[dt] = *(const bf16x8*)(Vc + quad * PLANE64 + R * 16);
      v1[dt] = *(const bf16x8*)(Vc + (quad + 4) * PLANE64 + R * 16);
    }
#pragma unroll
    for (int u = 0; u < 2; ++u) {
      // in-register redistribution: S[u][nt][pr] -> pf0/pf1 PV A-frags
      union { unsigned w[4]; bf16x8 v; } pf[2];
#pragma unroll
      for (int half = 0; half < 2; ++half)
#pragma unroll
        for (int pr = 0; pr < 2; ++pr) {
          uint2v a = __builtin_amdgcn_permlane32_swap(
              S[u][half * 2][pr], S[u][half * 2 + 1][pr], false, false);
          uint2v c = __builtin_amdgcn_permlane16_swap(a[0], a[1], false, false);
          pf[half].w[pr] = c[0];      // word pr   (k-offset 2*pr within 8)
          pf[half].w[pr + 2] = c[1];  // word pr+2 (k-offset 4+2*pr)
        }
      bf16x8 pf0 = pf[0].v, pf1 = pf[1].v;
      __builtin_amdgcn_s_setprio(1);
      acc_l[u] = mfma_bf16(pf0, ones, acc_l[u]);  // row sums -> l
      acc_l[u] = mfma_bf16(pf1, ones, acc_l[u]);
#pragma unroll
      for (int dt = 0; dt < 4; ++dt) {
        o_acc[u][dt] = mfma_bf16(pf0, v0[dt], o_acc[u][dt]);
        o_acc[u][dt] = mfma_bf16(pf1, v1[dt], o_acc[u][dt]);
      }
      __builtin_amdgcn_s_setprio(0);
    }
    if (it < 15) { mwc[0] = mwn[0]; mwc[1] = mwn[1]; }
  }

  // ---- in-block combine: half1 dumps partials to LDS, half0 merges --------
  __syncthreads();  // all staging/frag LDS traffic done; smem reusable
  float* cb = (float*)smem;  // 256 lanes * 40 f32 = 40 KB
  int cbase = (wl * 64 + lane) * 40;
  if (hw == 1) {
#pragma unroll
    for (int u = 0; u < 2; ++u) {
#pragma unroll
      for (int dt = 0; dt < 4; ++dt)
        *(floatx4*)(cb + cbase + (u * 4 + dt) * 4) = o_acc[u][dt];
      *(floatx4*)(cb + cbase + 32 + u * 4) = acc_l[u];
    }
  }
  __syncthreads();
  if (hw == 0) {
#pragma unroll
    for (int u = 0; u < 2; ++u) {
#pragma unroll
      for (int dt = 0; dt < 4; ++dt)
        o_acc[u][dt] += *(const floatx4*)(cb + cbase + (u * 4 + dt) * 4);
      acc_l[u] += *(const floatx4*)(cb + cbase + 32 + u * 4);
    }
#pragma unroll
    for (int u = 0; u < 2; ++u) {
      float lr[4];
#pragma unroll
      for (int r = 0; r < 4; ++r) lr[r] = 1.0f / acc_l[u][r];
#pragma unroll
      for (int dt = 0; dt < 4; ++dt)
#pragma unroll
        for (int r = 0; r < 4; ++r) {
          int qrow = q0 + wl * 32 + u * 16 + quad * 4 + r;
          int d = dt * 16 + lrow;
          int row = b * 2048 + qrow, col = h * 64 + d;
          Z[tix(row, col, 512)] = (bf16)(o_acc[u][dt][r] * lr[r]);
        }
    }
  }
}

// ---- layernorm: out = LN(a + s_f32) * g + b -------------------------------
// bf16 side (a_ read when A_BF16; out when OUT_BF16) uses the TILED layout
// (zn). f32 sides are linear (vx, s12, d_out).
template <bool A_BF16, bool OUT_BF16>
__global__ void __launch_bounds__(256) ln_k(const void* __restrict__ a_,
                                            const float* __restrict__ s,
                                            const float* __restrict__ g,
                                            const float* __restrict__ bta,
                                            void* __restrict__ out_) {
  int row = blockIdx.x * 4 + (threadIdx.x >> 6);
  int lane = threadIdx.x & 63;
  size_t base = (size_t)row * 512 + lane * 8;
  size_t tbase = tix(row, lane * 8, 512);
  float x[8];
  float4 sa = *(const float4*)(s + base);
  float4 sb = *(const float4*)(s + base + 4);
  if constexpr (A_BF16) {
    bf16x8 av = *(const bf16x8*)((const bf16*)a_ + tbase);
    x[0] = (float)av[0] + sa.x; x[1] = (float)av[1] + sa.y;
    x[2] = (float)av[2] + sa.z; x[3] = (float)av[3] + sa.w;
    x[4] = (float)av[4] + sb.x; x[5] = (float)av[5] + sb.y;
    x[6] = (float)av[6] + sb.z; x[7] = (float)av[7] + sb.w;
  } else {
    float4 a0 = *(const float4*)((const float*)a_ + base);
    float4 a1 = *(const float4*)((const float*)a_ + base + 4);
    x[0] = a0.x + sa.x; x[1] = a0.y + sa.y; x[2] = a0.z + sa.z; x[3] = a0.w + sa.w;
    x[4] = a1.x + sb.x; x[5] = a1.y + sb.y; x[6] = a1.z + sb.z; x[7] = a1.w + sb.w;
  }
  float sum = 0.f;
#pragma unroll
  for (int i = 0; i < 8; ++i) sum += x[i];
#pragma unroll
  for (int off = 1; off < 64; off <<= 1) sum += __shfl_xor(sum, off, 64);
  float mu = sum * (1.0f / 512.0f);
  float vs = 0.f;
#pragma unroll
  for (int i = 0; i < 8; ++i) { float d = x[i] - mu; vs += d * d; }
#pragma unroll
  for (int off = 1; off < 64; off <<= 1) vs += __shfl_xor(vs, off, 64);
  float rstd = rsqrtf(vs * (1.0f / 512.0f) + 1e-5f);
  float4 g0 = *(const float4*)(g + lane * 8);
  float4 g1 = *(const float4*)(g + lane * 8 + 4);
  float4 b0 = *(const float4*)(bta + lane * 8);
  float4 b1 = *(const float4*)(bta + lane * 8 + 4);
  float gg[8] = {g0.x, g0.y, g0.z, g0.w, g1.x, g1.y, g1.z, g1.w};
  float bb[8] = {b0.x, b0.y, b0.z, b0.w, b1.x, b1.y, b1.z, b1.w};
  if constexpr (OUT_BF16) {
    bf16x8 o;
#pragma unroll
    for (int i = 0; i < 8; ++i)
      o[i] = (bf16)((x[i] - mu) * rstd * gg[i] + bb[i]);
    *(bf16x8*)((bf16*)out_ + tbase) = o;
  } else {
    float4 o0, o1;
    o0.x = (x[0] - mu) * rstd * gg[0] + bb[0];
    o0.y = (x[1] - mu) * rstd * gg[1] + bb[1];
    o0.z = (x[2] - mu) * rstd * gg[2] + bb[2];
    o0.w = (x[3] - mu) * rstd * gg[3] + bb[3];
    o1.x = (x[4] - mu) * rstd * gg[4] + bb[4];
    o1.y = (x[5] - mu) * rstd * gg[5] + bb[5];
    o1.z = (x[6] - mu) * rstd * gg[6] + bb[6];
    o1.w = (x[7] - mu) * rstd * gg[7] + bb[7];
    *(float4*)((float*)out_ + base) = o0;
    *(float4*)((float*)out_ + base + 4) = o1;
  }
}

extern "C" void kernel_launch(void* const* d_in, const int* in_sizes, int n_in,
                              void* d_out, int out_size, void* d_ws, size_t ws_size,
                              hipStream_t stream) {
  const float* qx = (const float*)d_in[0];
  const float* kx = (const float*)d_in[1];
  const float* vx = (const float*)d_in[2];
  const int* maskPAD = (const int*)d_in[3];
  const float* wq = (const float*)d_in[4];
  const float* bq = (const float*)d_in[5];
  const float* wk = (const float*)d_in[6];
  const float* bk = (const float*)d_in[7];
  const float* wv = (const float*)d_in[8];
  const float* bv = (const float*)d_in[9];
  const float* wo = (const float*)d_in[10];
  const float* bo = (const float*)d_in[11];
  const float* w1 = (const float*)d_in[12];
  const float* b1 = (const float*)d_in[13];
  const float* w2 = (const float*)d_in[14];
  const float* b2 = (const float*)d_in[15];
  const float* g1 = (const float*)d_in[16];
  const float* be1 = (const float*)d_in[17];
  const float* g2 = (const float*)d_in[18];
  const float* be2 = (const float*)d_in[19];

  char* w = (char*)d_ws;
  size_t off = 0;
  auto alloc = [&](size_t bytes) {
    void* p = w + off;
    off += (bytes + 255) & ~(size_t)255;
    return p;
  };
  bf16* wqT = (bf16*)alloc(512 * 512 * 2);
  bf16* wkT = (bf16*)alloc(512 * 512 * 2);
  bf16* wvT = (bf16*)alloc(512 * 512 * 2);
  bf16* woT = (bf16*)alloc(512 * 512 * 2);
  bf16* w1T = (bf16*)alloc(2048 * 512 * 2);
  bf16* w2T = (bf16*)alloc(512 * 2048 * 2);
  unsigned long long* mbits = (unsigned long long*)alloc((size_t)4 * 2048 * 32 * 8);
  bf16* xb = (bf16*)alloc((size_t)3 * 4194304 * 2);  // cast qx,kx,vx (tiled)
  bf16* qh = (bf16*)alloc((size_t)8192 * 512 * 2);
  bf16* kh = (bf16*)alloc((size_t)8192 * 512 * 2);
  bf16* vt = (bf16*)alloc((size_t)8192 * 512 * 2);
  bf16* z = (bf16*)alloc((size_t)8192 * 512 * 2);
  float* s12 = (float*)qh;  // over qh+kh (dead after attn)
  bf16* zn = vt;            // vt dead after attn
  size_t h1_bytes = (size_t)8192 * 2048 * 2;
  bool big = (off + h1_bytes) <= ws_size;
  bf16* h1 = big ? (bf16*)alloc(h1_bytes) : z;

  // merged preprocessing: transposes + maskbits + cast3, one dispatch
  prep_k<<<11264, 256, 0, stream>>>(wq, wk, wv, wo, wqT, wkT, wvT, woT, w1, w1T,
                                    w2, w2T, maskPAD, mbits, qx, kx, vx, xb);
  // fused QKV (768 blocks), tiled A/B staging
  qkv_k<<<dim3(4, 192), 256, 0, stream>>>(xb, wqT, wkT, wvT, bq, bk, bv,
                                          qh, kh, vt);
  // flash attention -> z tiled (128 q-rows/block, 8 waves, kv-split)
  attn_k<<<dim3(16, 8, 4), 512, 0, stream>>>(qh, kh, vt, mbits, z);
  // out projection (TALL, 512 blocks) + LN1
  gemm_bt<4, true><<<dim3(8, 64), 256, 0, stream>>>(z, woT, bo, s12, 512, 512,
                                                    512, 512, 0);
  ln_k<false, true><<<2048, 256, 0, stream>>>(vx, s12, g1, be1, zn);
  if (big) {
    gemm_bt<3, false><<<dim3(16, 64), 256, 0, stream>>>(zn, w1T, b1, h1, 2048,
                                                        512, 512, 512, 0);
    gemm_bt<4, true><<<dim3(8, 64), 256, 0, stream>>>(h1, w2T, b2, s12, 512,
                                                      2048, 2048, 2048, 0);
  } else {
    for (int p = 0; p < 4; ++p) {
      gemm_bt<3, true><<<dim3(8, 64), 256, 0, stream>>>(
          zn, w1T + (size_t)p * 512 * 512, b1 + p * 512, h1, 512, 512, 512,
          512, 0);
      if (p == 0)
        gemm_bt<4, true><<<dim3(8, 64), 256, 0, stream>>>(
            h1, w2T, b2, s12, 512, 512, 512, 2048, p * 512);
      else
        gemm_bt<5, true><<<dim3(8, 64), 256, 0, stream>>>(
            h1, w2T, nullptr, s12, 512, 512, 512, 2048, p * 512);
    }
  }
  ln_k<true, false><<<2048, 256, 0, stream>>>(zn, s12, g2, be2, (float*)d_out);
}